// Round 7
// baseline (496.493 us; speedup 1.0000x reference)
//
#include <hip/hip_runtime.h>
#include <hip/hip_bf16.h>

#define N_ITEM 100000
#define N_USER 50000
#define N_ALL  150000
#define E1N 500000
#define E2N 250000
#define EALL (E1N + E2N)
#define NPAD 100352          // 98 * 1024, >= N_ITEM+1

// ---------------- workspace layout (bytes) ----------------
static constexpr size_t OFF_STATS = 0;                       // 512 f32 (zeroed)
static constexpr size_t OFF_HIST  = 2048;                    // NPAD ints (zeroed, adjacent -> one memset)
static constexpr size_t OFF_SCALE = OFF_HIST + (size_t)NPAD * 4;       // 512 f32
static constexpr size_t OFF_M     = OFF_SCALE + 2048;                  // 8 f32
static constexpr size_t OFF_EMBB  = OFF_M + 64;                        // bf16 emb [51,128] = 13056 B
static constexpr size_t OFF_WPACK = OFF_EMBB + 13312;        // 8 matrices bf16 frag-packed
static constexpr size_t OFF_QC    = OFF_WPACK + 8ull * 32768ull;       // bf16 [N_ALL,128] q1|q2
static constexpr size_t OFF_VC    = OFF_QC + (size_t)N_ALL * 256;      // bf16 v1|v2
static constexpr size_t OFF_K1    = OFF_VC + (size_t)N_ALL * 256;
static constexpr size_t OFF_K2    = OFF_K1 + (size_t)N_ITEM * 256;
static constexpr size_t OFF_SELF  = OFF_K2 + (size_t)N_ITEM * 256;
static constexpr size_t OFF_START = OFF_SELF + (size_t)N_ITEM * 256;   // NPAD ints (within-chunk exclusive)
static constexpr size_t OFF_CURSOR= OFF_START + (size_t)NPAD * 4;      // NPAD ints
static constexpr size_t OFF_BSUM  = OFF_CURSOR + (size_t)NPAD * 4;     // 128 ints
static constexpr size_t OFF_ORD   = OFF_BSUM + 1024;                   // EALL int2
static constexpr size_t OFF_AGG   = OFF_ORD + (size_t)EALL * 8 + 128;  // bf16 [N_ITEM,128]

// ---------------- helpers ----------------
__device__ __forceinline__ float bf2f(unsigned short u) {
    return __uint_as_float(((unsigned)u) << 16);
}
__device__ __forceinline__ unsigned short f2bf(float f) {
    unsigned u = __float_as_uint(f);
    u += 0x7fffu + ((u >> 16) & 1u);   // round-to-nearest-even
    return (unsigned short)(u >> 16);
}

typedef __attribute__((ext_vector_type(8))) short bf16x8;
typedef __attribute__((ext_vector_type(4))) float f32x4;

// ---------------- prologue: bn_stats + edge_hist + pack_w + emb->bf16 ------
// Block role order: stats first (long pole), then hist, then pack/emb fillers.
struct ProArgs {
    const float* w[8];
    const float* ft_item;
    const float* ft_user;
    const float* emb;
    const int* vid1;
    const int* vid2;
};
#define PRO_STAT 384    // 256 item + 128 user, float4 loads, 8 rows/blk/iter
#define PRO_HIST 733    // ceil(EALL/1024), 4 edges/thread
#define PRO_PACK 64
#define PRO_EMB  7      // 51*128/4 = 1632 threads

__global__ __launch_bounds__(256) void prologue(ProArgs A, char* __restrict__ ws) {
    __shared__ float r1[4][128], r2[4][128];
    int b = blockIdx.x, tid = threadIdx.x;
    if (b < PRO_STAT) {
        // BN stats: vectorized float4, 4 loads in flight per wave, LDS reduce.
        int type = (b >= 256) ? 1 : 0;
        int xb = type ? (b - 256) : b;
        int nb = type ? 128 : 256;
        const float* x = type ? A.ft_user : A.ft_item;
        int N = type ? N_USER : N_ITEM;
        float* sum = (float*)(ws + OFF_STATS) + type * 256;
        float* sq  = sum + 128;
        int c4 = (tid & 31) * 4;        // 4 columns per lane
        int rg = tid >> 5;              // row group 0..7
        int step = nb * 8;
        float s0 = 0.f, s1 = 0.f, s2 = 0.f, s3 = 0.f;
        float q0 = 0.f, q1 = 0.f, q2 = 0.f, q3 = 0.f;
        #pragma unroll 4
        for (int r = xb * 8 + rg; r < N; r += step) {
            float4 v = *(const float4*)(x + (size_t)r * 128 + c4);
            s0 += v.x; s1 += v.y; s2 += v.z; s3 += v.w;
            q0 = fmaf(v.x, v.x, q0); q1 = fmaf(v.y, v.y, q1);
            q2 = fmaf(v.z, v.z, q2); q3 = fmaf(v.w, v.w, q3);
        }
        // lane l and l+32 have the same columns (rows r, r+1): combine
        s0 += __shfl_xor(s0, 32); s1 += __shfl_xor(s1, 32);
        s2 += __shfl_xor(s2, 32); s3 += __shfl_xor(s3, 32);
        q0 += __shfl_xor(q0, 32); q1 += __shfl_xor(q1, 32);
        q2 += __shfl_xor(q2, 32); q3 += __shfl_xor(q3, 32);
        int wv = tid >> 6;
        if ((tid & 63) < 32) {
            *(float4*)&r1[wv][c4] = make_float4(s0, s1, s2, s3);
            *(float4*)&r2[wv][c4] = make_float4(q0, q1, q2, q3);
        }
        __syncthreads();
        if (tid < 128) {
            float a  = r1[0][tid] + r1[1][tid] + r1[2][tid] + r1[3][tid];
            float bb = r2[0][tid] + r2[1][tid] + r2[2][tid] + r2[3][tid];
            atomicAdd(&sum[tid], a);
            atomicAdd(&sq[tid], bb);
        }
    } else if (b < PRO_STAT + PRO_HIST) {
        // dst histogram, 4 edges/thread (E1N, EALL divisible by 4)
        int e4 = ((b - PRO_STAT) * 256 + tid) * 4;
        if (e4 < EALL) {
            int* hist = (int*)(ws + OFF_HIST);
            int4 v;
            if (e4 < E1N) v = *(const int4*)(A.vid1 + e4);
            else          v = *(const int4*)(A.vid2 + (e4 - E1N));
            atomicAdd(&hist[v.x], 1);
            atomicAdd(&hist[v.y], 1);
            atomicAdd(&hist[v.z], 1);
            atomicAdd(&hist[v.w], 1);
        }
    } else if (b < PRO_STAT + PRO_HIST + PRO_PACK) {
        // pack weights into MFMA fragment order:
        // frag(m,t,kt,lane) = W[n=t*16+(lane&15)][k=kt*32+(lane>>4)*8 + j], j=0..7
        unsigned short* dst = (unsigned short*)(ws + OFF_WPACK);
        int gid = (b - PRO_STAT - PRO_HIST) * 256 + tid;
        int m = gid >> 11, rem = gid & 2047;
        int t = rem >> 8, kt = (rem >> 6) & 3, lane = rem & 63;
        int n = t * 16 + (lane & 15);
        int k0 = kt * 32 + (lane >> 4) * 8;
        const float* wrow = A.w[m] + n * 128 + k0;
        float4 w0 = *(const float4*)wrow;
        float4 w1 = *(const float4*)(wrow + 4);
        ushort4 o0 = make_ushort4(f2bf(w0.x), f2bf(w0.y), f2bf(w0.z), f2bf(w0.w));
        ushort4 o1 = make_ushort4(f2bf(w1.x), f2bf(w1.y), f2bf(w1.z), f2bf(w1.w));
        *(ushort4*)(dst + (size_t)gid * 8)     = o0;
        *(ushort4*)(dst + (size_t)gid * 8 + 4) = o1;
    } else {
        int gid = (b - PRO_STAT - PRO_HIST - PRO_PACK) * 256 + tid;   // 4 elems/thread
        if (gid * 4 < 51 * 128) {
            float4 v = *(const float4*)(A.emb + gid * 4);
            ushort4 o = make_ushort4(f2bf(v.x), f2bf(v.y), f2bf(v.z), f2bf(v.w));
            *(ushort4*)((unsigned short*)(ws + OFF_EMBB) + gid * 4) = o;
        }
    }
}

// ---------------- scan_partial: per-1024-chunk exclusive scan --------------
__global__ __launch_bounds__(1024) void scan_partial(char* __restrict__ ws) {
    __shared__ int sd[1024];
    const int* hist = (const int*)(ws + OFF_HIST);
    int* start  = (int*)(ws + OFF_START);
    int* cursor = (int*)(ws + OFF_CURSOR);
    int* bsum   = (int*)(ws + OFF_BSUM);
    int t = threadIdx.x;
    int gid = blockIdx.x * 1024 + t;
    int v = hist[gid];
    sd[t] = v;
    __syncthreads();
    #pragma unroll
    for (int off = 1; off < 1024; off <<= 1) {
        int x = (t >= off) ? sd[t - off] : 0;
        __syncthreads();
        sd[t] += x;
        __syncthreads();
    }
    int ex = sd[t] - v;        // exclusive within chunk
    start[gid] = ex;
    cursor[gid] = ex;
    if (t == 1023) bsum[blockIdx.x] = sd[t];
}

// ---------------- mid: bn_finalize (block 0) + scan_top (block 1) ----------
__global__ __launch_bounds__(256) void mid(const float* __restrict__ g_i, const float* __restrict__ b_i,
                                           const float* __restrict__ g_u, const float* __restrict__ b_u,
                                           const float* __restrict__ ae1, const float* __restrict__ ae2,
                                           char* __restrict__ ws) {
    __shared__ int sd[128];
    int t = threadIdx.x;
    if (blockIdx.x == 0) {
        const float* stats = (const float*)(ws + OFF_STATS);
        float* scale = (float*)(ws + OFF_SCALE);
        float* M     = (float*)(ws + OFF_M);
        int type = t >> 7, c = t & 127;
        float N = type ? (float)N_USER : (float)N_ITEM;
        float su = stats[type * 256 + c];
        float sq = stats[type * 256 + 128 + c];
        float mu = su / N;
        float var = sq / N - mu * mu;
        float rstd = rsqrtf(var + 1e-5f);
        float g = type ? g_u[c] : g_i[c];
        float b = type ? b_u[c] : b_i[c];
        scale[type * 256 + c]       = g * rstd;
        scale[type * 256 + 128 + c] = b - mu * g * rstd;
        if (t < 8) {
            float m1 = 0.f, m2 = 0.f;
            for (int j = 0; j < 16; j++) {
                m1 += fmaxf(ae1[t * 16 + j], 0.f);
                m2 += fmaxf(ae2[t * 16 + j], 0.f);
            }
            M[t] = fmaxf(m1, m2);   // uniform per-head shift, both etypes
        }
    } else {
        int* bsum = (int*)(ws + OFF_BSUM);
        int v = 0;
        if (t < 128) { v = (t < 98) ? bsum[t] : 0; sd[t] = v; }
        __syncthreads();
        #pragma unroll
        for (int off = 1; off < 128; off <<= 1) {
            int x = 0;
            if (t < 128 && t >= off) x = sd[t - off];
            __syncthreads();
            if (t < 128) sd[t] += x;
            __syncthreads();
        }
        if (t < 98) bsum[t] = sd[t] - v;   // exclusive chunk offsets
    }
}

// ---------------- transform: 32 rows/wave, DIRECT MFMA stores (no LDS) -----
// (R4 code frozen: VGPR 36, no LDS, no spill; only the occupancy bound is
// raised 5->8 -- VGPR cap 64 >= natural 36, so no spill pressure added.)
struct TArgs {
    const float* x;              // raw f32 features
    const float* bias0;          // bias for matrix 0 (q), may be null
    int N;
    int scaleOff;                // 0 item, 256 user
    int nmat;
    int wtIdx[5];
    unsigned short* out[5];
};
struct ScArgs {
    const int* uid1; const int* vid1; const int* cnt1;
    const int* uid2; const int* vid2;
};

#define TB_I 782   // ceil(100000/128)
#define TB_U 391   // ceil(50000/128)
#define SC_B 733   // ceil(EALL/1024), 4 edges/thread

__global__ __launch_bounds__(256, 8) void transform(TArgs AI, TArgs AU, ScArgs S, char* __restrict__ ws) {
    int b = blockIdx.x;
    if (b >= TB_I + TB_U) {
        // ---- edge scatter (CSR records), 4 edges per thread ----
        int e0 = ((b - TB_I - TB_U) * 256 + threadIdx.x) * 4;
        if (e0 < EALL) {
            int* cursor = (int*)(ws + OFF_CURSOR);
            const int* bsum = (const int*)(ws + OFF_BSUM);
            int2* ord = (int2*)(ws + OFF_ORD);
            int4 u, c, d;
            if (e0 < E1N) {
                u = *(const int4*)(S.uid1 + e0);
                d = *(const int4*)(S.vid1 + e0);
                c = *(const int4*)(S.cnt1 + e0);
            } else {
                int ee = e0 - E1N;
                u = *(const int4*)(S.uid2 + ee);
                d = *(const int4*)(S.vid2 + ee);
                u.x += N_ITEM; u.y += N_ITEM; u.z += N_ITEM; u.w += N_ITEM;
                c = make_int4(-1, -1, -1, -1);
            }
            int us[4] = {u.x, u.y, u.z, u.w};
            int ds[4] = {d.x, d.y, d.z, d.w};
            int cs[4] = {c.x, c.y, c.z, c.w};
            #pragma unroll
            for (int j = 0; j < 4; j++) {
                int dst = ds[j];
                int pos = atomicAdd(&cursor[dst], 1) + bsum[dst >> 10];
                int2 rec; rec.x = us[j]; rec.y = cs[j];
                ord[pos] = rec;
            }
        }
        return;
    }
    const TArgs& A = (b < TB_I) ? AI : AU;
    int blk = (b < TB_I) ? b : b - TB_I;

    const unsigned short* wpack = (const unsigned short*)(ws + OFF_WPACK);
    const float* scaleb = (const float*)(ws + OFF_SCALE) + A.scaleOff;
    int tid = threadIdx.x, lane = tid & 63;
    int wv = tid >> 6;
    int l16 = lane & 15, quad = lane >> 4;
    int base = blk * 128 + wv * 32;

    // B-fragments: BN-applied feature rows (bf16), zero-padded beyond N
    bf16x8 bfr[2][4];
    #pragma unroll
    for (int kt = 0; kt < 4; kt++) {
        int c0 = kt * 32 + quad * 8;
        float4 sc0 = *(const float4*)(scaleb + c0);
        float4 sc1 = *(const float4*)(scaleb + c0 + 4);
        float4 bi0 = *(const float4*)(scaleb + 128 + c0);
        float4 bi1 = *(const float4*)(scaleb + 128 + c0 + 4);
        #pragma unroll
        for (int it = 0; it < 2; it++) {
            int gr = base + it * 16 + l16;
            bf16x8 f = {0, 0, 0, 0, 0, 0, 0, 0};
            if (gr < A.N) {
                const float* p = A.x + (size_t)gr * 128 + c0;
                float4 v0 = *(const float4*)p;
                float4 v1 = *(const float4*)(p + 4);
                f[0] = (short)f2bf(fmaf(v0.x, sc0.x, bi0.x));
                f[1] = (short)f2bf(fmaf(v0.y, sc0.y, bi0.y));
                f[2] = (short)f2bf(fmaf(v0.z, sc0.z, bi0.z));
                f[3] = (short)f2bf(fmaf(v0.w, sc0.w, bi0.w));
                f[4] = (short)f2bf(fmaf(v1.x, sc1.x, bi1.x));
                f[5] = (short)f2bf(fmaf(v1.y, sc1.y, bi1.y));
                f[6] = (short)f2bf(fmaf(v1.z, sc1.z, bi1.z));
                f[7] = (short)f2bf(fmaf(v1.w, sc1.w, bi1.w));
            }
            bfr[it][kt] = f;
        }
    }

    int gr0 = base + l16;          // it = 0 row
    int gr1 = base + 16 + l16;     // it = 1 row
    bool in0 = gr0 < A.N, in1 = gr1 < A.N;

    for (int m = 0; m < A.nmat; m++) {
        const unsigned short* wp = wpack + (size_t)A.wtIdx[m] * 16384;
        unsigned short* outp = A.out[m];
        const float* bias = (m == 0) ? A.bias0 : nullptr;
        #pragma unroll
        for (int nt = 0; nt < 8; nt++) {
            bf16x8 a4[4];
            #pragma unroll
            for (int kt = 0; kt < 4; kt++)
                a4[kt] = *(const bf16x8*)(wp + (size_t)((nt * 4 + kt) * 64 + lane) * 8);
            f32x4 acc0 = {0.f, 0.f, 0.f, 0.f};
            if (bias) {
                float4 bv = *(const float4*)(bias + nt * 16 + quad * 4);
                acc0[0] = bv.x; acc0[1] = bv.y; acc0[2] = bv.z; acc0[3] = bv.w;
            }
            f32x4 acc1 = acc0;
            #pragma unroll
            for (int kt = 0; kt < 4; kt++) {
                acc0 = __builtin_amdgcn_mfma_f32_16x16x32_bf16(a4[kt], bfr[0][kt], acc0, 0, 0, 0);
                acc1 = __builtin_amdgcn_mfma_f32_16x16x32_bf16(a4[kt], bfr[1][kt], acc1, 0, 0, 0);
            }
            ushort4 o0 = make_ushort4(f2bf(acc0[0]), f2bf(acc0[1]), f2bf(acc0[2]), f2bf(acc0[3]));
            ushort4 o1 = make_ushort4(f2bf(acc1[0]), f2bf(acc1[1]), f2bf(acc1[2]), f2bf(acc1[3]));
            int co = nt * 16 + quad * 4;
            if (in0) *(ushort4*)(outp + (size_t)gr0 * 128 + co) = o0;
            if (in1) *(ushort4*)(outp + (size_t)gr1 * 128 + co) = o1;
        }
    }
}

// ---------------- fused edge phase: wave per dst, 4 slots, pipelined -------
// 16 lanes per edge slot, 8 dims/lane (16B loads). Next edge's record +
// q-row + emb-row are prefetched BEFORE computing the current edge, so the
// ~600cy gather latency overlaps the sigmoid chain. v-row loads at iteration
// top (latency partially covered by the score compute).
__global__ __launch_bounds__(256, 7) void edge_agg(const float* __restrict__ ae1, const float* __restrict__ ae2,
                                                   char* __restrict__ ws) {
    const unsigned short* qc = (const unsigned short*)(ws + OFF_QC);
    const unsigned short* vc = (const unsigned short*)(ws + OFF_VC);
    const unsigned short* k1 = (const unsigned short*)(ws + OFF_K1);
    const unsigned short* k2 = (const unsigned short*)(ws + OFF_K2);
    const unsigned short* embb = (const unsigned short*)(ws + OFF_EMBB);
    const int* start = (const int*)(ws + OFF_START);
    const int* bsum  = (const int*)(ws + OFF_BSUM);
    const int2* ord = (const int2*)(ws + OFF_ORD);
    const float* M = (const float*)(ws + OFF_M);
    unsigned short* aggb = (unsigned short*)(ws + OFF_AGG);

    int tid = threadIdx.x;
    int lane = tid & 63;
    int slot = lane >> 4;     // 4 edge slots per wave
    int l = lane & 15;        // 16 lanes per slot
    int d0 = l << 3;          // 8 dims per lane
    int h = l >> 1;           // head (DH=16 => 2 lanes/head)
    int dst = blockIdx.x * 4 + (tid >> 6);
    if (dst >= N_ITEM) return;

    float mh = M[h];
    float ae1v[8], ae2v[8], k1v[8], k2v[8];
    {
        float4 t0 = *(const float4*)(ae1 + d0);
        float4 t1 = *(const float4*)(ae1 + d0 + 4);
        ae1v[0]=t0.x; ae1v[1]=t0.y; ae1v[2]=t0.z; ae1v[3]=t0.w;
        ae1v[4]=t1.x; ae1v[5]=t1.y; ae1v[6]=t1.z; ae1v[7]=t1.w;
        float4 t2 = *(const float4*)(ae2 + d0);
        float4 t3 = *(const float4*)(ae2 + d0 + 4);
        ae2v[0]=t2.x; ae2v[1]=t2.y; ae2v[2]=t2.z; ae2v[3]=t2.w;
        ae2v[4]=t3.x; ae2v[5]=t3.y; ae2v[6]=t3.z; ae2v[7]=t3.w;
        bf16x8 k1p = *(const bf16x8*)(k1 + (size_t)dst * 128 + d0);
        bf16x8 k2p = *(const bf16x8*)(k2 + (size_t)dst * 128 + d0);
        #pragma unroll
        for (int j = 0; j < 8; j++) {
            k1v[j] = bf2f((unsigned short)k1p[j]);
            k2v[j] = bf2f((unsigned short)k2p[j]);
        }
    }

    int beg = start[dst] + bsum[dst >> 10];
    int end = start[dst + 1] + bsum[(dst + 1) >> 10];
    float a[8] = {0.f, 0.f, 0.f, 0.f, 0.f, 0.f, 0.f, 0.f};
    float s = 0.f;

    int i = beg + slot;
    if (i < end) {
        int2 rec = ord[i];
        bf16x8 qp = *(const bf16x8*)(qc + (size_t)rec.x * 128 + d0);
        bf16x8 ep = *(const bf16x8*)(embb + (size_t)(rec.y >= 0 ? rec.y : 0) * 128 + d0);
        while (true) {
            bf16x8 vp = *(const bf16x8*)(vc + (size_t)rec.x * 128 + d0);
            int inext = i + 4;
            bool more = inext < end;
            int ipf = more ? inext : i;
            int2 recn = ord[ipf];                 // next record (L2-hot)
            bf16x8 qpn = *(const bf16x8*)(qc + (size_t)recn.x * 128 + d0);
            bf16x8 epn = *(const bf16x8*)(embb + (size_t)(recn.y >= 0 ? recn.y : 0) * 128 + d0);
            bool t1e = rec.y >= 0;
            float t = 0.f;
            #pragma unroll
            for (int j = 0; j < 8; j++) {
                float kv = t1e ? (k1v[j] + bf2f((unsigned short)ep[j])) : k2v[j];
                float x = bf2f((unsigned short)qp[j]) + kv;
                float sg = __builtin_amdgcn_rcpf(1.f + __expf(-x));
                t = fmaf(t1e ? ae1v[j] : ae2v[j], sg, t);
            }
            t += __shfl_xor(t, 1);            // head reduce (2 lanes)
            float ex = __expf(t - mh);
            s += ex;
            #pragma unroll
            for (int j = 0; j < 8; j++)
                a[j] = fmaf(ex, bf2f((unsigned short)vp[j]), a[j]);
            if (!more) break;
            i = inext; rec = recn; qp = qpn; ep = epn;
        }
    }
    // combine the four edge slots
    s += __shfl_xor(s, 16);
    s += __shfl_xor(s, 32);
    #pragma unroll
    for (int j = 0; j < 8; j++) {
        a[j] += __shfl_xor(a[j], 16);
        a[j] += __shfl_xor(a[j], 32);
    }
    if (slot == 0) {
        float inv = (s > 0.f) ? __builtin_amdgcn_rcpf(s) : 0.f;
        bf16x8 o;
        #pragma unroll
        for (int j = 0; j < 8; j++)
            o[j] = (short)f2bf(a[j] * inv);
        *(bf16x8*)(aggb + (size_t)dst * 128 + d0) = o;   // 16 lanes x 16B = 256B/row
    }
}

// ---------------- final: relu(agg @ Wagg.T + b + selfterm), LDS-staged -----
#define FPITCH 132

__global__ __launch_bounds__(256) void final_mfma(const float* __restrict__ b_agg,
                                                  float* __restrict__ out, char* __restrict__ ws) {
    __shared__ float stg[4][16 * FPITCH];
    const unsigned short* aggb = (const unsigned short*)(ws + OFF_AGG);
    const unsigned short* selft = (const unsigned short*)(ws + OFF_SELF);
    const unsigned short* wp = (const unsigned short*)(ws + OFF_WPACK) + 7ull * 16384;
    int tid = threadIdx.x, lane = tid & 63, wv = tid >> 6;
    int l16 = lane & 15, quad = lane >> 4;
    int base = blockIdx.x * 256 + wv * 64;
    float* st = stg[wv];

    // B-fragments from agg rows: direct bf16x8 loads (agg stored bf16)
    bf16x8 bfr[4][4];
    #pragma unroll
    for (int it = 0; it < 4; it++) {
        int gr = base + it * 16 + l16;
        #pragma unroll
        for (int kt = 0; kt < 4; kt++) {
            bf16x8 f = {0, 0, 0, 0, 0, 0, 0, 0};
            if (gr < N_ITEM)
                f = *(const bf16x8*)(aggb + (size_t)gr * 128 + kt * 32 + quad * 8);
            bfr[it][kt] = f;
        }
    }

    #pragma unroll
    for (int it = 0; it < 4; it++) {
        #pragma unroll
        for (int nt = 0; nt < 8; nt++) {
            bf16x8 a4[4];
            #pragma unroll
            for (int kt = 0; kt < 4; kt++)
                a4[kt] = *(const bf16x8*)(wp + (size_t)((nt * 4 + kt) * 64 + lane) * 8);
            float4 bv = *(const float4*)(b_agg + nt * 16 + quad * 4);
            f32x4 acc = {bv.x, bv.y, bv.z, bv.w};
            #pragma unroll
            for (int kt = 0; kt < 4; kt++)
                acc = __builtin_amdgcn_mfma_f32_16x16x32_bf16(a4[kt], bfr[it][kt], acc, 0, 0, 0);
            *(f32x4*)(st + l16 * FPITCH + nt * 16 + quad * 4) = acc;
        }
        // wave-synchronous readback: coalesced add-self + relu + store
        #pragma unroll
        for (int i = 0; i < 8; i++) {
            int chunk = i * 64 + lane;
            int row = chunk >> 5, c4 = (chunk & 31) * 4;
            int gr = base + it * 16 + row;
            if (gr < N_ITEM) {
                float4 v = *(const float4*)(st + row * FPITCH + c4);
                size_t idx = (size_t)gr * 128 + c4;
                ushort4 sf = *(const ushort4*)(selft + idx);
                float4 o;
                o.x = fmaxf(v.x + bf2f(sf.x), 0.f);
                o.y = fmaxf(v.y + bf2f(sf.y), 0.f);
                o.z = fmaxf(v.z + bf2f(sf.z), 0.f);
                o.w = fmaxf(v.w + bf2f(sf.w), 0.f);
                *(float4*)(out + idx) = o;
            }
        }
    }
}

// ---------------- host ----------------
extern "C" void kernel_launch(void* const* d_in, const int* in_sizes, int n_in,
                              void* d_out, int out_size, void* d_ws, size_t ws_size,
                              hipStream_t stream) {
    char* ws = (char*)d_ws;

    const float* ft_item = (const float*)d_in[0];
    const float* ft_user = (const float*)d_in[1];
    const float* bng_i = (const float*)d_in[2];
    const float* bnb_i = (const float*)d_in[3];
    const float* bng_u = (const float*)d_in[4];
    const float* bnb_u = (const float*)d_in[5];
    const float* Wq1 = (const float*)d_in[6];
    const float* bq1 = (const float*)d_in[7];
    const float* Wk1 = (const float*)d_in[8];
    const float* Wv1 = (const float*)d_in[9];
    const float* ae1 = (const float*)d_in[10];
    const float* emb = (const float*)d_in[11];
    const float* Wq2 = (const float*)d_in[12];
    const float* bq2 = (const float*)d_in[13];
    const float* Wk2 = (const float*)d_in[14];
    const float* Wv2 = (const float*)d_in[15];
    const float* ae2 = (const float*)d_in[16];
    const float* W_agg = (const float*)d_in[17];
    const float* b_agg = (const float*)d_in[18];
    const float* W_self = (const float*)d_in[19];
    const int* uid1 = (const int*)d_in[20];
    const int* vid1 = (const int*)d_in[21];
    const int* cnt1 = (const int*)d_in[22];
    const int* uid2 = (const int*)d_in[23];
    const int* vid2 = (const int*)d_in[24];
    float* out = (float*)d_out;

    // single memset: stats (2KB) + hist (adjacent)
    hipMemsetAsync(ws + OFF_STATS, 0, 2048 + (size_t)NPAD * 4, stream);

    // 1. prologue: BN stats + dst histogram + pack weights + emb->bf16
    ProArgs pa;
    pa.w[0] = Wq1; pa.w[1] = Wk1; pa.w[2] = Wv1; pa.w[3] = Wk2;
    pa.w[4] = W_self; pa.w[5] = Wq2; pa.w[6] = Wv2; pa.w[7] = W_agg;
    pa.ft_item = ft_item; pa.ft_user = ft_user; pa.emb = emb;
    pa.vid1 = vid1; pa.vid2 = vid2;
    prologue<<<PRO_STAT + PRO_HIST + PRO_PACK + PRO_EMB, 256, 0, stream>>>(pa, ws);

    // 2. per-chunk exclusive scan
    scan_partial<<<98, 1024, 0, stream>>>(ws);

    // 3. BN finalize + chunk-offset scan
    mid<<<2, 256, 0, stream>>>(bng_i, bnb_i, bng_u, bnb_u, ae1, ae2, ws);

    // 4+5. all 7 node-transform GEMMs + co-scheduled edge scatter (tail)
    TArgs ti, tu;
    ti.x = ft_item; ti.bias0 = bq1; ti.N = N_ITEM; ti.scaleOff = 0; ti.nmat = 5;
    ti.wtIdx[0] = 0; ti.wtIdx[1] = 1; ti.wtIdx[2] = 2; ti.wtIdx[3] = 3; ti.wtIdx[4] = 4;
    unsigned short* QC = (unsigned short*)(ws + OFF_QC);
    unsigned short* VC = (unsigned short*)(ws + OFF_VC);
    ti.out[0] = QC;
    ti.out[1] = (unsigned short*)(ws + OFF_K1);
    ti.out[2] = VC;
    ti.out[3] = (unsigned short*)(ws + OFF_K2);
    ti.out[4] = (unsigned short*)(ws + OFF_SELF);
    tu.x = ft_user; tu.bias0 = bq2; tu.N = N_USER; tu.scaleOff = 256; tu.nmat = 2;
    tu.wtIdx[0] = 5; tu.wtIdx[1] = 6; tu.wtIdx[2] = 0; tu.wtIdx[3] = 0; tu.wtIdx[4] = 0;
    tu.out[0] = QC + (size_t)N_ITEM * 128;
    tu.out[1] = VC + (size_t)N_ITEM * 128;
    tu.out[2] = tu.out[3] = tu.out[4] = tu.out[0];
    ScArgs sa;
    sa.uid1 = uid1; sa.vid1 = vid1; sa.cnt1 = cnt1; sa.uid2 = uid2; sa.vid2 = vid2;
    transform<<<TB_I + TB_U + SC_B, 256, 0, stream>>>(ti, tu, sa, ws);

    // 6. fused edge softmax+aggregate (4 slots/wave, pipelined gathers)
    edge_agg<<<(N_ITEM + 3) / 4, 256, 0, stream>>>(ae1, ae2, ws);

    // 7. final GEMM + self + relu
    final_mfma<<<(N_ITEM + 255) / 256, 256, 0, stream>>>(b_agg, out, ws);
}

// Round 8
// 429.786 us; speedup vs baseline: 1.1552x; 1.1552x over previous
//
#include <hip/hip_runtime.h>
#include <hip/hip_bf16.h>

#define N_ITEM 100000
#define N_USER 50000
#define N_ALL  150000
#define E1N 500000
#define E2N 250000
#define EALL (E1N + E2N)
#define NPAD 100352          // 98 * 1024, >= N_ITEM+1

// ---------------- workspace layout (bytes) ----------------
static constexpr size_t OFF_STATS = 0;                       // 512 f32 (zeroed)
static constexpr size_t OFF_HIST  = 2048;                    // NPAD ints (zeroed, adjacent -> one memset)
static constexpr size_t OFF_SCALE = OFF_HIST + (size_t)NPAD * 4;       // 512 f32
static constexpr size_t OFF_M     = OFF_SCALE + 2048;                  // 8 f32
static constexpr size_t OFF_EMBB  = OFF_M + 64;                        // bf16 emb [51,128] = 13056 B
static constexpr size_t OFF_WPACK = OFF_EMBB + 13312;        // 8 matrices bf16 frag-packed
static constexpr size_t OFF_QC    = OFF_WPACK + 8ull * 32768ull;       // bf16 [N_ALL,128] q1|q2
static constexpr size_t OFF_VC    = OFF_QC + (size_t)N_ALL * 256;      // bf16 v1|v2
static constexpr size_t OFF_K1    = OFF_VC + (size_t)N_ALL * 256;
static constexpr size_t OFF_K2    = OFF_K1 + (size_t)N_ITEM * 256;
static constexpr size_t OFF_SELF  = OFF_K2 + (size_t)N_ITEM * 256;
static constexpr size_t OFF_START = OFF_SELF + (size_t)N_ITEM * 256;   // NPAD ints (within-chunk exclusive)
static constexpr size_t OFF_CURSOR= OFF_START + (size_t)NPAD * 4;      // NPAD ints
static constexpr size_t OFF_BSUM  = OFF_CURSOR + (size_t)NPAD * 4;     // 128 ints
static constexpr size_t OFF_ORD   = OFF_BSUM + 1024;                   // EALL int2
static constexpr size_t OFF_AGG   = OFF_ORD + (size_t)EALL * 8 + 128;  // bf16 [N_ITEM,128]

// ---------------- helpers ----------------
__device__ __forceinline__ float bf2f(unsigned short u) {
    return __uint_as_float(((unsigned)u) << 16);
}
__device__ __forceinline__ unsigned short f2bf(float f) {
    unsigned u = __float_as_uint(f);
    u += 0x7fffu + ((u >> 16) & 1u);   // round-to-nearest-even
    return (unsigned short)(u >> 16);
}

typedef __attribute__((ext_vector_type(8))) short bf16x8;
typedef __attribute__((ext_vector_type(4))) float f32x4;

// ---------------- prologue: bn_stats + edge_hist + pack_w + emb->bf16 ------
// Block role order: stats first (long pole), then hist, then pack/emb fillers.
struct ProArgs {
    const float* w[8];
    const float* ft_item;
    const float* ft_user;
    const float* emb;
    const int* vid1;
    const int* vid2;
};
#define PRO_STAT 384    // 256 item + 128 user, float4 loads, 8 rows/blk/iter
#define PRO_HIST 733    // ceil(EALL/1024), 4 edges/thread
#define PRO_PACK 64
#define PRO_EMB  7      // 51*128/4 = 1632 threads

__global__ __launch_bounds__(256) void prologue(ProArgs A, char* __restrict__ ws) {
    __shared__ float r1[4][128], r2[4][128];
    int b = blockIdx.x, tid = threadIdx.x;
    if (b < PRO_STAT) {
        // BN stats: vectorized float4, 4 loads in flight per wave, LDS reduce.
        int type = (b >= 256) ? 1 : 0;
        int xb = type ? (b - 256) : b;
        int nb = type ? 128 : 256;
        const float* x = type ? A.ft_user : A.ft_item;
        int N = type ? N_USER : N_ITEM;
        float* sum = (float*)(ws + OFF_STATS) + type * 256;
        float* sq  = sum + 128;
        int c4 = (tid & 31) * 4;        // 4 columns per lane
        int rg = tid >> 5;              // row group 0..7
        int step = nb * 8;
        float s0 = 0.f, s1 = 0.f, s2 = 0.f, s3 = 0.f;
        float q0 = 0.f, q1 = 0.f, q2 = 0.f, q3 = 0.f;
        #pragma unroll 4
        for (int r = xb * 8 + rg; r < N; r += step) {
            float4 v = *(const float4*)(x + (size_t)r * 128 + c4);
            s0 += v.x; s1 += v.y; s2 += v.z; s3 += v.w;
            q0 = fmaf(v.x, v.x, q0); q1 = fmaf(v.y, v.y, q1);
            q2 = fmaf(v.z, v.z, q2); q3 = fmaf(v.w, v.w, q3);
        }
        // lane l and l+32 have the same columns (rows r, r+1): combine
        s0 += __shfl_xor(s0, 32); s1 += __shfl_xor(s1, 32);
        s2 += __shfl_xor(s2, 32); s3 += __shfl_xor(s3, 32);
        q0 += __shfl_xor(q0, 32); q1 += __shfl_xor(q1, 32);
        q2 += __shfl_xor(q2, 32); q3 += __shfl_xor(q3, 32);
        int wv = tid >> 6;
        if ((tid & 63) < 32) {
            *(float4*)&r1[wv][c4] = make_float4(s0, s1, s2, s3);
            *(float4*)&r2[wv][c4] = make_float4(q0, q1, q2, q3);
        }
        __syncthreads();
        if (tid < 128) {
            float a  = r1[0][tid] + r1[1][tid] + r1[2][tid] + r1[3][tid];
            float bb = r2[0][tid] + r2[1][tid] + r2[2][tid] + r2[3][tid];
            atomicAdd(&sum[tid], a);
            atomicAdd(&sq[tid], bb);
        }
    } else if (b < PRO_STAT + PRO_HIST) {
        // dst histogram, 4 edges/thread (E1N, EALL divisible by 4)
        int e4 = ((b - PRO_STAT) * 256 + tid) * 4;
        if (e4 < EALL) {
            int* hist = (int*)(ws + OFF_HIST);
            int4 v;
            if (e4 < E1N) v = *(const int4*)(A.vid1 + e4);
            else          v = *(const int4*)(A.vid2 + (e4 - E1N));
            atomicAdd(&hist[v.x], 1);
            atomicAdd(&hist[v.y], 1);
            atomicAdd(&hist[v.z], 1);
            atomicAdd(&hist[v.w], 1);
        }
    } else if (b < PRO_STAT + PRO_HIST + PRO_PACK) {
        // pack weights into MFMA fragment order:
        // frag(m,t,kt,lane) = W[n=t*16+(lane&15)][k=kt*32+(lane>>4)*8 + j], j=0..7
        unsigned short* dst = (unsigned short*)(ws + OFF_WPACK);
        int gid = (b - PRO_STAT - PRO_HIST) * 256 + tid;
        int m = gid >> 11, rem = gid & 2047;
        int t = rem >> 8, kt = (rem >> 6) & 3, lane = rem & 63;
        int n = t * 16 + (lane & 15);
        int k0 = kt * 32 + (lane >> 4) * 8;
        const float* wrow = A.w[m] + n * 128 + k0;
        float4 w0 = *(const float4*)wrow;
        float4 w1 = *(const float4*)(wrow + 4);
        ushort4 o0 = make_ushort4(f2bf(w0.x), f2bf(w0.y), f2bf(w0.z), f2bf(w0.w));
        ushort4 o1 = make_ushort4(f2bf(w1.x), f2bf(w1.y), f2bf(w1.z), f2bf(w1.w));
        *(ushort4*)(dst + (size_t)gid * 8)     = o0;
        *(ushort4*)(dst + (size_t)gid * 8 + 4) = o1;
    } else {
        int gid = (b - PRO_STAT - PRO_HIST - PRO_PACK) * 256 + tid;   // 4 elems/thread
        if (gid * 4 < 51 * 128) {
            float4 v = *(const float4*)(A.emb + gid * 4);
            ushort4 o = make_ushort4(f2bf(v.x), f2bf(v.y), f2bf(v.z), f2bf(v.w));
            *(ushort4*)((unsigned short*)(ws + OFF_EMBB) + gid * 4) = o;
        }
    }
}

// ---------------- scan_partial: per-1024-chunk exclusive scan --------------
__global__ __launch_bounds__(1024) void scan_partial(char* __restrict__ ws) {
    __shared__ int sd[1024];
    const int* hist = (const int*)(ws + OFF_HIST);
    int* start  = (int*)(ws + OFF_START);
    int* cursor = (int*)(ws + OFF_CURSOR);
    int* bsum   = (int*)(ws + OFF_BSUM);
    int t = threadIdx.x;
    int gid = blockIdx.x * 1024 + t;
    int v = hist[gid];
    sd[t] = v;
    __syncthreads();
    #pragma unroll
    for (int off = 1; off < 1024; off <<= 1) {
        int x = (t >= off) ? sd[t - off] : 0;
        __syncthreads();
        sd[t] += x;
        __syncthreads();
    }
    int ex = sd[t] - v;        // exclusive within chunk
    start[gid] = ex;
    cursor[gid] = ex;
    if (t == 1023) bsum[blockIdx.x] = sd[t];
}

// ---------------- mid: bn_finalize (block 0) + scan_top (block 1) ----------
__global__ __launch_bounds__(256) void mid(const float* __restrict__ g_i, const float* __restrict__ b_i,
                                           const float* __restrict__ g_u, const float* __restrict__ b_u,
                                           const float* __restrict__ ae1, const float* __restrict__ ae2,
                                           char* __restrict__ ws) {
    __shared__ int sd[128];
    int t = threadIdx.x;
    if (blockIdx.x == 0) {
        const float* stats = (const float*)(ws + OFF_STATS);
        float* scale = (float*)(ws + OFF_SCALE);
        float* M     = (float*)(ws + OFF_M);
        int type = t >> 7, c = t & 127;
        float N = type ? (float)N_USER : (float)N_ITEM;
        float su = stats[type * 256 + c];
        float sq = stats[type * 256 + 128 + c];
        float mu = su / N;
        float var = sq / N - mu * mu;
        float rstd = rsqrtf(var + 1e-5f);
        float g = type ? g_u[c] : g_i[c];
        float b = type ? b_u[c] : b_i[c];
        scale[type * 256 + c]       = g * rstd;
        scale[type * 256 + 128 + c] = b - mu * g * rstd;
        if (t < 8) {
            float m1 = 0.f, m2 = 0.f;
            for (int j = 0; j < 16; j++) {
                m1 += fmaxf(ae1[t * 16 + j], 0.f);
                m2 += fmaxf(ae2[t * 16 + j], 0.f);
            }
            M[t] = fmaxf(m1, m2);   // uniform per-head shift, both etypes
        }
    } else {
        int* bsum = (int*)(ws + OFF_BSUM);
        int v = 0;
        if (t < 128) { v = (t < 98) ? bsum[t] : 0; sd[t] = v; }
        __syncthreads();
        #pragma unroll
        for (int off = 1; off < 128; off <<= 1) {
            int x = 0;
            if (t < 128 && t >= off) x = sd[t - off];
            __syncthreads();
            if (t < 128) sd[t] += x;
            __syncthreads();
        }
        if (t < 98) bsum[t] = sd[t] - v;   // exclusive chunk offsets
    }
}

// ---------------- transform: 32 rows/wave, DIRECT MFMA stores (no LDS) -----
// (R4/R5 code+bound byte-exact: VGPR 36, no LDS, no spill, 105 us measured.
//  DO NOT change the launch bound: 6 and 8 both flipped codegen to spill.)
struct TArgs {
    const float* x;              // raw f32 features
    const float* bias0;          // bias for matrix 0 (q), may be null
    int N;
    int scaleOff;                // 0 item, 256 user
    int nmat;
    int wtIdx[5];
    unsigned short* out[5];
};
struct ScArgs {
    const int* uid1; const int* vid1; const int* cnt1;
    const int* uid2; const int* vid2;
};

#define TB_I 782   // ceil(100000/128)
#define TB_U 391   // ceil(50000/128)
#define SC_B 733   // ceil(EALL/1024), 4 edges/thread

__global__ __launch_bounds__(256, 5) void transform(TArgs AI, TArgs AU, ScArgs S, char* __restrict__ ws) {
    int b = blockIdx.x;
    if (b >= TB_I + TB_U) {
        // ---- edge scatter (CSR records), 4 edges per thread ----
        int e0 = ((b - TB_I - TB_U) * 256 + threadIdx.x) * 4;
        if (e0 < EALL) {
            int* cursor = (int*)(ws + OFF_CURSOR);
            const int* bsum = (const int*)(ws + OFF_BSUM);
            int2* ord = (int2*)(ws + OFF_ORD);
            int4 u, c, d;
            if (e0 < E1N) {
                u = *(const int4*)(S.uid1 + e0);
                d = *(const int4*)(S.vid1 + e0);
                c = *(const int4*)(S.cnt1 + e0);
            } else {
                int ee = e0 - E1N;
                u = *(const int4*)(S.uid2 + ee);
                d = *(const int4*)(S.vid2 + ee);
                u.x += N_ITEM; u.y += N_ITEM; u.z += N_ITEM; u.w += N_ITEM;
                c = make_int4(-1, -1, -1, -1);
            }
            int us[4] = {u.x, u.y, u.z, u.w};
            int ds[4] = {d.x, d.y, d.z, d.w};
            int cs[4] = {c.x, c.y, c.z, c.w};
            #pragma unroll
            for (int j = 0; j < 4; j++) {
                int dst = ds[j];
                int pos = atomicAdd(&cursor[dst], 1) + bsum[dst >> 10];
                int2 rec; rec.x = us[j]; rec.y = cs[j];
                ord[pos] = rec;
            }
        }
        return;
    }
    const TArgs& A = (b < TB_I) ? AI : AU;
    int blk = (b < TB_I) ? b : b - TB_I;

    const unsigned short* wpack = (const unsigned short*)(ws + OFF_WPACK);
    const float* scaleb = (const float*)(ws + OFF_SCALE) + A.scaleOff;
    int tid = threadIdx.x, lane = tid & 63;
    int wv = tid >> 6;
    int l16 = lane & 15, quad = lane >> 4;
    int base = blk * 128 + wv * 32;

    // B-fragments: BN-applied feature rows (bf16), zero-padded beyond N
    bf16x8 bfr[2][4];
    #pragma unroll
    for (int kt = 0; kt < 4; kt++) {
        int c0 = kt * 32 + quad * 8;
        float4 sc0 = *(const float4*)(scaleb + c0);
        float4 sc1 = *(const float4*)(scaleb + c0 + 4);
        float4 bi0 = *(const float4*)(scaleb + 128 + c0);
        float4 bi1 = *(const float4*)(scaleb + 128 + c0 + 4);
        #pragma unroll
        for (int it = 0; it < 2; it++) {
            int gr = base + it * 16 + l16;
            bf16x8 f = {0, 0, 0, 0, 0, 0, 0, 0};
            if (gr < A.N) {
                const float* p = A.x + (size_t)gr * 128 + c0;
                float4 v0 = *(const float4*)p;
                float4 v1 = *(const float4*)(p + 4);
                f[0] = (short)f2bf(fmaf(v0.x, sc0.x, bi0.x));
                f[1] = (short)f2bf(fmaf(v0.y, sc0.y, bi0.y));
                f[2] = (short)f2bf(fmaf(v0.z, sc0.z, bi0.z));
                f[3] = (short)f2bf(fmaf(v0.w, sc0.w, bi0.w));
                f[4] = (short)f2bf(fmaf(v1.x, sc1.x, bi1.x));
                f[5] = (short)f2bf(fmaf(v1.y, sc1.y, bi1.y));
                f[6] = (short)f2bf(fmaf(v1.z, sc1.z, bi1.z));
                f[7] = (short)f2bf(fmaf(v1.w, sc1.w, bi1.w));
            }
            bfr[it][kt] = f;
        }
    }

    int gr0 = base + l16;          // it = 0 row
    int gr1 = base + 16 + l16;     // it = 1 row
    bool in0 = gr0 < A.N, in1 = gr1 < A.N;

    for (int m = 0; m < A.nmat; m++) {
        const unsigned short* wp = wpack + (size_t)A.wtIdx[m] * 16384;
        unsigned short* outp = A.out[m];
        const float* bias = (m == 0) ? A.bias0 : nullptr;
        #pragma unroll
        for (int nt = 0; nt < 8; nt++) {
            bf16x8 a4[4];
            #pragma unroll
            for (int kt = 0; kt < 4; kt++)
                a4[kt] = *(const bf16x8*)(wp + (size_t)((nt * 4 + kt) * 64 + lane) * 8);
            f32x4 acc0 = {0.f, 0.f, 0.f, 0.f};
            if (bias) {
                float4 bv = *(const float4*)(bias + nt * 16 + quad * 4);
                acc0[0] = bv.x; acc0[1] = bv.y; acc0[2] = bv.z; acc0[3] = bv.w;
            }
            f32x4 acc1 = acc0;
            #pragma unroll
            for (int kt = 0; kt < 4; kt++) {
                acc0 = __builtin_amdgcn_mfma_f32_16x16x32_bf16(a4[kt], bfr[0][kt], acc0, 0, 0, 0);
                acc1 = __builtin_amdgcn_mfma_f32_16x16x32_bf16(a4[kt], bfr[1][kt], acc1, 0, 0, 0);
            }
            ushort4 o0 = make_ushort4(f2bf(acc0[0]), f2bf(acc0[1]), f2bf(acc0[2]), f2bf(acc0[3]));
            ushort4 o1 = make_ushort4(f2bf(acc1[0]), f2bf(acc1[1]), f2bf(acc1[2]), f2bf(acc1[3]));
            int co = nt * 16 + quad * 4;
            if (in0) *(ushort4*)(outp + (size_t)gr0 * 128 + co) = o0;
            if (in1) *(ushort4*)(outp + (size_t)gr1 * 128 + co) = o1;
        }
    }
}

// ---------------- fused edge phase: wave per dst, 4 slots, ushort8 loads ---
// (R5 byte-exact: 107.8 us measured, VGPR 40, no spill. The R7 deep-pipeline
//  variant spilled to scratch (+196MB WRITE) -- do not re-add live state.)
__global__ __launch_bounds__(256, 6) void edge_agg(const float* __restrict__ ae1, const float* __restrict__ ae2,
                                                   char* __restrict__ ws) {
    const unsigned short* qc = (const unsigned short*)(ws + OFF_QC);
    const unsigned short* vc = (const unsigned short*)(ws + OFF_VC);
    const unsigned short* k1 = (const unsigned short*)(ws + OFF_K1);
    const unsigned short* k2 = (const unsigned short*)(ws + OFF_K2);
    const unsigned short* embb = (const unsigned short*)(ws + OFF_EMBB);
    const int* start = (const int*)(ws + OFF_START);
    const int* bsum  = (const int*)(ws + OFF_BSUM);
    const int2* ord = (const int2*)(ws + OFF_ORD);
    const float* M = (const float*)(ws + OFF_M);
    unsigned short* aggb = (unsigned short*)(ws + OFF_AGG);

    int tid = threadIdx.x;
    int lane = tid & 63;
    int slot = lane >> 4;     // 4 edge slots per wave
    int l = lane & 15;        // 16 lanes per slot
    int d0 = l << 3;          // 8 dims per lane
    int h = l >> 1;           // head (DH=16 => 2 lanes/head)
    int dst = blockIdx.x * 4 + (tid >> 6);
    if (dst >= N_ITEM) return;

    float mh = M[h];
    float ae1v[8], ae2v[8], k1v[8], k2v[8];
    {
        float4 t0 = *(const float4*)(ae1 + d0);
        float4 t1 = *(const float4*)(ae1 + d0 + 4);
        ae1v[0]=t0.x; ae1v[1]=t0.y; ae1v[2]=t0.z; ae1v[3]=t0.w;
        ae1v[4]=t1.x; ae1v[5]=t1.y; ae1v[6]=t1.z; ae1v[7]=t1.w;
        float4 t2 = *(const float4*)(ae2 + d0);
        float4 t3 = *(const float4*)(ae2 + d0 + 4);
        ae2v[0]=t2.x; ae2v[1]=t2.y; ae2v[2]=t2.z; ae2v[3]=t2.w;
        ae2v[4]=t3.x; ae2v[5]=t3.y; ae2v[6]=t3.z; ae2v[7]=t3.w;
        bf16x8 k1p = *(const bf16x8*)(k1 + (size_t)dst * 128 + d0);
        bf16x8 k2p = *(const bf16x8*)(k2 + (size_t)dst * 128 + d0);
        #pragma unroll
        for (int j = 0; j < 8; j++) {
            k1v[j] = bf2f((unsigned short)k1p[j]);
            k2v[j] = bf2f((unsigned short)k2p[j]);
        }
    }

    int beg = start[dst] + bsum[dst >> 10];
    int end = start[dst + 1] + bsum[(dst + 1) >> 10];
    float a[8] = {0.f, 0.f, 0.f, 0.f, 0.f, 0.f, 0.f, 0.f};
    float s = 0.f;

    int i = beg + slot;
    if (i < end) {
        int2 rec = ord[i];
        while (true) {
            int inext = i + 4;
            int ipf = (inext < end) ? inext : (end - 1);
            int2 recn = ord[ipf];                     // prefetch next record
            bool t1e = rec.y >= 0;
            bf16x8 qp = *(const bf16x8*)(qc + (size_t)rec.x * 128 + d0);
            bf16x8 vp = *(const bf16x8*)(vc + (size_t)rec.x * 128 + d0);
            bf16x8 ep = *(const bf16x8*)(embb + (size_t)(t1e ? rec.y : 0) * 128 + d0);
            float t = 0.f;
            #pragma unroll
            for (int j = 0; j < 8; j++) {
                float kv = t1e ? (k1v[j] + bf2f((unsigned short)ep[j])) : k2v[j];
                float x = bf2f((unsigned short)qp[j]) + kv;
                float sg = __builtin_amdgcn_rcpf(1.f + __expf(-x));
                t = fmaf(t1e ? ae1v[j] : ae2v[j], sg, t);
            }
            t += __shfl_xor(t, 1);            // head reduce (2 lanes)
            float ex = __expf(t - mh);
            s += ex;
            #pragma unroll
            for (int j = 0; j < 8; j++)
                a[j] = fmaf(ex, bf2f((unsigned short)vp[j]), a[j]);
            if (inext >= end) break;
            i = inext; rec = recn;
        }
    }
    // combine the four edge slots
    s += __shfl_xor(s, 16);
    s += __shfl_xor(s, 32);
    #pragma unroll
    for (int j = 0; j < 8; j++) {
        a[j] += __shfl_xor(a[j], 16);
        a[j] += __shfl_xor(a[j], 32);
    }
    if (slot == 0) {
        float inv = (s > 0.f) ? __builtin_amdgcn_rcpf(s) : 0.f;
        bf16x8 o;
        #pragma unroll
        for (int j = 0; j < 8; j++)
            o[j] = (short)f2bf(a[j] * inv);
        *(bf16x8*)(aggb + (size_t)dst * 128 + d0) = o;   // 16 lanes x 16B = 256B/row
    }
}

// ---------------- final: relu(agg @ Wagg.T + b + selfterm), DIRECT stores --
// LDS staging removed (was 33.8KB -> 4 blocks/CU cap). D-frag mapping: lane
// (l16,quad) holds row base+it*16+l16, cols nt*16+quad*4 -> 16B f32x4 store,
// 4 quads give 64B contiguity per (row,nt). nt-outer: each weight fragment
// loaded once, 4 independent MFMA chains (it=0..3) per nt.
__global__ __launch_bounds__(256) void final_mfma(const float* __restrict__ b_agg,
                                                  float* __restrict__ out, char* __restrict__ ws) {
    const unsigned short* aggb = (const unsigned short*)(ws + OFF_AGG);
    const unsigned short* selft = (const unsigned short*)(ws + OFF_SELF);
    const unsigned short* wp = (const unsigned short*)(ws + OFF_WPACK) + 7ull * 16384;
    int tid = threadIdx.x, lane = tid & 63, wv = tid >> 6;
    int l16 = lane & 15, quad = lane >> 4;
    int base = blockIdx.x * 256 + wv * 64;

    // B-fragments from agg rows: direct bf16x8 loads (agg stored bf16)
    bf16x8 bfr[4][4];
    #pragma unroll
    for (int it = 0; it < 4; it++) {
        int gr = base + it * 16 + l16;
        #pragma unroll
        for (int kt = 0; kt < 4; kt++) {
            bf16x8 f = {0, 0, 0, 0, 0, 0, 0, 0};
            if (gr < N_ITEM)
                f = *(const bf16x8*)(aggb + (size_t)gr * 128 + kt * 32 + quad * 8);
            bfr[it][kt] = f;
        }
    }

    #pragma unroll
    for (int nt = 0; nt < 8; nt++) {
        bf16x8 a4[4];
        #pragma unroll
        for (int kt = 0; kt < 4; kt++)
            a4[kt] = *(const bf16x8*)(wp + (size_t)((nt * 4 + kt) * 64 + lane) * 8);
        float4 bv = *(const float4*)(b_agg + nt * 16 + quad * 4);
        f32x4 acc0 = {bv.x, bv.y, bv.z, bv.w};
        f32x4 acc1 = acc0, acc2 = acc0, acc3 = acc0;
        #pragma unroll
        for (int kt = 0; kt < 4; kt++) {
            acc0 = __builtin_amdgcn_mfma_f32_16x16x32_bf16(a4[kt], bfr[0][kt], acc0, 0, 0, 0);
            acc1 = __builtin_amdgcn_mfma_f32_16x16x32_bf16(a4[kt], bfr[1][kt], acc1, 0, 0, 0);
            acc2 = __builtin_amdgcn_mfma_f32_16x16x32_bf16(a4[kt], bfr[2][kt], acc2, 0, 0, 0);
            acc3 = __builtin_amdgcn_mfma_f32_16x16x32_bf16(a4[kt], bfr[3][kt], acc3, 0, 0, 0);
        }
        int co = nt * 16 + quad * 4;
        #pragma unroll
        for (int it = 0; it < 4; it++) {
            f32x4 acc = (it == 0) ? acc0 : (it == 1) ? acc1 : (it == 2) ? acc2 : acc3;
            int gr = base + it * 16 + l16;
            if (gr < N_ITEM) {
                size_t idx = (size_t)gr * 128 + co;
                ushort4 sf = *(const ushort4*)(selft + idx);
                float4 o;
                o.x = fmaxf(acc[0] + bf2f(sf.x), 0.f);
                o.y = fmaxf(acc[1] + bf2f(sf.y), 0.f);
                o.z = fmaxf(acc[2] + bf2f(sf.z), 0.f);
                o.w = fmaxf(acc[3] + bf2f(sf.w), 0.f);
                *(float4*)(out + idx) = o;
            }
        }
    }
}

// ---------------- host ----------------
extern "C" void kernel_launch(void* const* d_in, const int* in_sizes, int n_in,
                              void* d_out, int out_size, void* d_ws, size_t ws_size,
                              hipStream_t stream) {
    char* ws = (char*)d_ws;

    const float* ft_item = (const float*)d_in[0];
    const float* ft_user = (const float*)d_in[1];
    const float* bng_i = (const float*)d_in[2];
    const float* bnb_i = (const float*)d_in[3];
    const float* bng_u = (const float*)d_in[4];
    const float* bnb_u = (const float*)d_in[5];
    const float* Wq1 = (const float*)d_in[6];
    const float* bq1 = (const float*)d_in[7];
    const float* Wk1 = (const float*)d_in[8];
    const float* Wv1 = (const float*)d_in[9];
    const float* ae1 = (const float*)d_in[10];
    const float* emb = (const float*)d_in[11];
    const float* Wq2 = (const float*)d_in[12];
    const float* bq2 = (const float*)d_in[13];
    const float* Wk2 = (const float*)d_in[14];
    const float* Wv2 = (const float*)d_in[15];
    const float* ae2 = (const float*)d_in[16];
    const float* W_agg = (const float*)d_in[17];
    const float* b_agg = (const float*)d_in[18];
    const float* W_self = (const float*)d_in[19];
    const int* uid1 = (const int*)d_in[20];
    const int* vid1 = (const int*)d_in[21];
    const int* cnt1 = (const int*)d_in[22];
    const int* uid2 = (const int*)d_in[23];
    const int* vid2 = (const int*)d_in[24];
    float* out = (float*)d_out;

    // single memset: stats (2KB) + hist (adjacent)
    hipMemsetAsync(ws + OFF_STATS, 0, 2048 + (size_t)NPAD * 4, stream);

    // 1. prologue: BN stats + dst histogram + pack weights + emb->bf16
    ProArgs pa;
    pa.w[0] = Wq1; pa.w[1] = Wk1; pa.w[2] = Wv1; pa.w[3] = Wk2;
    pa.w[4] = W_self; pa.w[5] = Wq2; pa.w[6] = Wv2; pa.w[7] = W_agg;
    pa.ft_item = ft_item; pa.ft_user = ft_user; pa.emb = emb;
    pa.vid1 = vid1; pa.vid2 = vid2;
    prologue<<<PRO_STAT + PRO_HIST + PRO_PACK + PRO_EMB, 256, 0, stream>>>(pa, ws);

    // 2. per-chunk exclusive scan
    scan_partial<<<98, 1024, 0, stream>>>(ws);

    // 3. BN finalize + chunk-offset scan
    mid<<<2, 256, 0, stream>>>(bng_i, bnb_i, bng_u, bnb_u, ae1, ae2, ws);

    // 4+5. all 7 node-transform GEMMs + co-scheduled edge scatter (tail)
    TArgs ti, tu;
    ti.x = ft_item; ti.bias0 = bq1; ti.N = N_ITEM; ti.scaleOff = 0; ti.nmat = 5;
    ti.wtIdx[0] = 0; ti.wtIdx[1] = 1; ti.wtIdx[2] = 2; ti.wtIdx[3] = 3; ti.wtIdx[4] = 4;
    unsigned short* QC = (unsigned short*)(ws + OFF_QC);
    unsigned short* VC = (unsigned short*)(ws + OFF_VC);
    ti.out[0] = QC;
    ti.out[1] = (unsigned short*)(ws + OFF_K1);
    ti.out[2] = VC;
    ti.out[3] = (unsigned short*)(ws + OFF_K2);
    ti.out[4] = (unsigned short*)(ws + OFF_SELF);
    tu.x = ft_user; tu.bias0 = bq2; tu.N = N_USER; tu.scaleOff = 256; tu.nmat = 2;
    tu.wtIdx[0] = 5; tu.wtIdx[1] = 6; tu.wtIdx[2] = 0; tu.wtIdx[3] = 0; tu.wtIdx[4] = 0;
    tu.out[0] = QC + (size_t)N_ITEM * 128;
    tu.out[1] = VC + (size_t)N_ITEM * 128;
    tu.out[2] = tu.out[3] = tu.out[4] = tu.out[0];
    ScArgs sa;
    sa.uid1 = uid1; sa.vid1 = vid1; sa.cnt1 = cnt1; sa.uid2 = uid2; sa.vid2 = vid2;
    transform<<<TB_I + TB_U + SC_B, 256, 0, stream>>>(ti, tu, sa, ws);

    // 6. fused edge softmax+aggregate (4 slots/wave, 16B loads)
    edge_agg<<<(N_ITEM + 3) / 4, 256, 0, stream>>>(ae1, ae2, ws);

    // 7. final GEMM + self + relu (direct stores, no LDS)
    final_mfma<<<(N_ITEM + 255) / 256, 256, 0, stream>>>(b_agg, out, ws);
}

// Round 9
// 425.090 us; speedup vs baseline: 1.1680x; 1.0110x over previous
//
#include <hip/hip_runtime.h>
#include <hip/hip_bf16.h>

#define N_ITEM 100000
#define N_USER 50000
#define N_ALL  150000
#define E1N 500000
#define E2N 250000
#define EALL (E1N + E2N)
#define NPAD 100352          // 98 * 1024, >= N_ITEM+1

// ---------------- workspace layout (bytes) ----------------
static constexpr size_t OFF_STATS = 0;                       // 512 f32 (zeroed)
static constexpr size_t OFF_HIST  = 2048;                    // NPAD ints (zeroed)
static constexpr size_t OFF_CNT   = OFF_HIST + (size_t)NPAD * 4;       // 64 B (zeroed): scan ticket
static constexpr size_t OFF_SCALE = OFF_CNT + 64;                      // 512 f32
static constexpr size_t OFF_M     = OFF_SCALE + 2048;                  // 8 f32
static constexpr size_t OFF_EMBB  = OFF_M + 64;                        // bf16 emb [51,128] = 13056 B
static constexpr size_t OFF_WPACK = OFF_EMBB + 13312;        // 8 matrices bf16 frag-packed
static constexpr size_t OFF_QC    = OFF_WPACK + 8ull * 32768ull;       // bf16 [N_ALL,128] q1|q2
static constexpr size_t OFF_VC    = OFF_QC + (size_t)N_ALL * 256;      // bf16 v1|v2
static constexpr size_t OFF_K1    = OFF_VC + (size_t)N_ALL * 256;
static constexpr size_t OFF_K2    = OFF_K1 + (size_t)N_ITEM * 256;
static constexpr size_t OFF_SELF  = OFF_K2 + (size_t)N_ITEM * 256;
static constexpr size_t OFF_START = OFF_SELF + (size_t)N_ITEM * 256;   // NPAD ints (within-chunk exclusive)
static constexpr size_t OFF_CURSOR= OFF_START + (size_t)NPAD * 4;      // NPAD ints
static constexpr size_t OFF_BSUM  = OFF_CURSOR + (size_t)NPAD * 4;     // 128 ints
static constexpr size_t OFF_ORD   = OFF_BSUM + 1024;                   // EALL int2
static constexpr size_t OFF_AGG   = OFF_ORD + (size_t)EALL * 8 + 128;  // bf16 [N_ITEM,128]

// ---------------- helpers ----------------
__device__ __forceinline__ float bf2f(unsigned short u) {
    return __uint_as_float(((unsigned)u) << 16);
}
__device__ __forceinline__ unsigned short f2bf(float f) {
    unsigned u = __float_as_uint(f);
    u += 0x7fffu + ((u >> 16) & 1u);   // round-to-nearest-even
    return (unsigned short)(u >> 16);
}

typedef __attribute__((ext_vector_type(8))) short bf16x8;
typedef __attribute__((ext_vector_type(4))) float f32x4;

// ---------------- prologue: bn_stats + edge_hist + pack_w + emb->bf16 ------
// Stats blocks doubled (768) to halve the per-block serial iteration count
// (the prologue's long pole). Guarded loop -> any block count is correct.
struct ProArgs {
    const float* w[8];
    const float* ft_item;
    const float* ft_user;
    const float* emb;
    const int* vid1;
    const int* vid2;
};
#define PRO_STAT 768    // 512 item + 256 user, float4 loads, 8 rows/blk/iter
#define PRO_HIST 733    // ceil(EALL/1024), 4 edges/thread
#define PRO_PACK 64
#define PRO_EMB  7      // 51*128/4 = 1632 threads

__global__ __launch_bounds__(256) void prologue(ProArgs A, char* __restrict__ ws) {
    __shared__ float r1[4][128], r2[4][128];
    int b = blockIdx.x, tid = threadIdx.x;
    if (b < PRO_STAT) {
        // BN stats: vectorized float4, 4 loads in flight per wave, LDS reduce.
        int type = (b >= 512) ? 1 : 0;
        int xb = type ? (b - 512) : b;
        int nb = type ? 256 : 512;
        const float* x = type ? A.ft_user : A.ft_item;
        int N = type ? N_USER : N_ITEM;
        float* sum = (float*)(ws + OFF_STATS) + type * 256;
        float* sq  = sum + 128;
        int c4 = (tid & 31) * 4;        // 4 columns per lane
        int rg = tid >> 5;              // row group 0..7
        int step = nb * 8;
        float s0 = 0.f, s1 = 0.f, s2 = 0.f, s3 = 0.f;
        float q0 = 0.f, q1 = 0.f, q2 = 0.f, q3 = 0.f;
        #pragma unroll 4
        for (int r = xb * 8 + rg; r < N; r += step) {
            float4 v = *(const float4*)(x + (size_t)r * 128 + c4);
            s0 += v.x; s1 += v.y; s2 += v.z; s3 += v.w;
            q0 = fmaf(v.x, v.x, q0); q1 = fmaf(v.y, v.y, q1);
            q2 = fmaf(v.z, v.z, q2); q3 = fmaf(v.w, v.w, q3);
        }
        // lane l and l+32 have the same columns (rows r, r+1): combine
        s0 += __shfl_xor(s0, 32); s1 += __shfl_xor(s1, 32);
        s2 += __shfl_xor(s2, 32); s3 += __shfl_xor(s3, 32);
        q0 += __shfl_xor(q0, 32); q1 += __shfl_xor(q1, 32);
        q2 += __shfl_xor(q2, 32); q3 += __shfl_xor(q3, 32);
        int wv = tid >> 6;
        if ((tid & 63) < 32) {
            *(float4*)&r1[wv][c4] = make_float4(s0, s1, s2, s3);
            *(float4*)&r2[wv][c4] = make_float4(q0, q1, q2, q3);
        }
        __syncthreads();
        if (tid < 128) {
            float a  = r1[0][tid] + r1[1][tid] + r1[2][tid] + r1[3][tid];
            float bb = r2[0][tid] + r2[1][tid] + r2[2][tid] + r2[3][tid];
            atomicAdd(&sum[tid], a);
            atomicAdd(&sq[tid], bb);
        }
    } else if (b < PRO_STAT + PRO_HIST) {
        // dst histogram, 4 edges/thread (E1N, EALL divisible by 4)
        int e4 = ((b - PRO_STAT) * 256 + tid) * 4;
        if (e4 < EALL) {
            int* hist = (int*)(ws + OFF_HIST);
            int4 v;
            if (e4 < E1N) v = *(const int4*)(A.vid1 + e4);
            else          v = *(const int4*)(A.vid2 + (e4 - E1N));
            atomicAdd(&hist[v.x], 1);
            atomicAdd(&hist[v.y], 1);
            atomicAdd(&hist[v.z], 1);
            atomicAdd(&hist[v.w], 1);
        }
    } else if (b < PRO_STAT + PRO_HIST + PRO_PACK) {
        // pack weights into MFMA fragment order:
        // frag(m,t,kt,lane) = W[n=t*16+(lane&15)][k=kt*32+(lane>>4)*8 + j], j=0..7
        unsigned short* dst = (unsigned short*)(ws + OFF_WPACK);
        int gid = (b - PRO_STAT - PRO_HIST) * 256 + tid;
        int m = gid >> 11, rem = gid & 2047;
        int t = rem >> 8, kt = (rem >> 6) & 3, lane = rem & 63;
        int n = t * 16 + (lane & 15);
        int k0 = kt * 32 + (lane >> 4) * 8;
        const float* wrow = A.w[m] + n * 128 + k0;
        float4 w0 = *(const float4*)wrow;
        float4 w1 = *(const float4*)(wrow + 4);
        ushort4 o0 = make_ushort4(f2bf(w0.x), f2bf(w0.y), f2bf(w0.z), f2bf(w0.w));
        ushort4 o1 = make_ushort4(f2bf(w1.x), f2bf(w1.y), f2bf(w1.z), f2bf(w1.w));
        *(ushort4*)(dst + (size_t)gid * 8)     = o0;
        *(ushort4*)(dst + (size_t)gid * 8 + 4) = o1;
    } else {
        int gid = (b - PRO_STAT - PRO_HIST - PRO_PACK) * 256 + tid;   // 4 elems/thread
        if (gid * 4 < 51 * 128) {
            float4 v = *(const float4*)(A.emb + gid * 4);
            ushort4 o = make_ushort4(f2bf(v.x), f2bf(v.y), f2bf(v.z), f2bf(v.w));
            *(ushort4*)((unsigned short*)(ws + OFF_EMBB) + gid * 4) = o;
        }
    }
}

// ---------------- scan_fused: chunk scans + top-scan (last block) ----------
// Blocks 0..97: per-1024-chunk exclusive scan; publish chunk sum; ticket.
// Last chunk block through the ticket does the 98-entry top-scan.
// Block 98: independent BN-finalize + per-head shift M (was kernel `mid`).
__global__ __launch_bounds__(1024) void scan_fused(const float* __restrict__ g_i, const float* __restrict__ b_i,
                                                   const float* __restrict__ g_u, const float* __restrict__ b_u,
                                                   const float* __restrict__ ae1, const float* __restrict__ ae2,
                                                   char* __restrict__ ws) {
    __shared__ int sd[1024];
    __shared__ int lastBlk;
    int t = threadIdx.x;
    int b = blockIdx.x;
    if (b == 98) {
        // ---- BN finalize (depends only on prologue stats) ----
        if (t < 256) {
            const float* stats = (const float*)(ws + OFF_STATS);
            float* scale = (float*)(ws + OFF_SCALE);
            float* M     = (float*)(ws + OFF_M);
            int type = t >> 7, c = t & 127;
            float N = type ? (float)N_USER : (float)N_ITEM;
            float su = stats[type * 256 + c];
            float sq = stats[type * 256 + 128 + c];
            float mu = su / N;
            float var = sq / N - mu * mu;
            float rstd = rsqrtf(var + 1e-5f);
            float g = type ? g_u[c] : g_i[c];
            float bb = type ? b_u[c] : b_i[c];
            scale[type * 256 + c]       = g * rstd;
            scale[type * 256 + 128 + c] = bb - mu * g * rstd;
            if (t < 8) {
                float m1 = 0.f, m2 = 0.f;
                for (int j = 0; j < 16; j++) {
                    m1 += fmaxf(ae1[t * 16 + j], 0.f);
                    m2 += fmaxf(ae2[t * 16 + j], 0.f);
                }
                M[t] = fmaxf(m1, m2);   // uniform per-head shift, both etypes
            }
        }
        return;
    }
    const int* hist = (const int*)(ws + OFF_HIST);
    int* start  = (int*)(ws + OFF_START);
    int* cursor = (int*)(ws + OFF_CURSOR);
    int* bsum   = (int*)(ws + OFF_BSUM);
    int* cnt    = (int*)(ws + OFF_CNT);
    int gid = b * 1024 + t;
    int v = hist[gid];
    sd[t] = v;
    __syncthreads();
    #pragma unroll
    for (int off = 1; off < 1024; off <<= 1) {
        int x = (t >= off) ? sd[t - off] : 0;
        __syncthreads();
        sd[t] += x;
        __syncthreads();
    }
    int ex = sd[t] - v;        // exclusive within chunk
    start[gid] = ex;
    cursor[gid] = ex;
    if (t == 1023) {
        bsum[b] = sd[t];
        __threadfence();       // publish chunk sum device-wide
    }
    __syncthreads();
    if (t == 0) lastBlk = (atomicAdd(cnt, 1) == 97) ? 1 : 0;
    __syncthreads();
    if (lastBlk) {
        __threadfence();       // acquire: all bsum writes visible
        int v2 = 0;
        if (t < 128) { v2 = (t < 98) ? bsum[t] : 0; sd[t] = v2; }
        __syncthreads();
        #pragma unroll
        for (int off = 1; off < 128; off <<= 1) {
            int x = 0;
            if (t < 128 && t >= off) x = sd[t - off];
            __syncthreads();
            if (t < 128) sd[t] += x;
            __syncthreads();
        }
        if (t < 98) bsum[t] = sd[t] - v2;   // exclusive chunk offsets
    }
}

// ---------------- transform: 32 rows/wave, DIRECT MFMA stores (no LDS) -----
// (R4/R5/R8 code+bound byte-exact: VGPR 36, no LDS, no spill, ~110 us.
//  DO NOT change the launch bound: 6 and 8 both flipped codegen to spill.)
struct TArgs {
    const float* x;              // raw f32 features
    const float* bias0;          // bias for matrix 0 (q), may be null
    int N;
    int scaleOff;                // 0 item, 256 user
    int nmat;
    int wtIdx[5];
    unsigned short* out[5];
};
struct ScArgs {
    const int* uid1; const int* vid1; const int* cnt1;
    const int* uid2; const int* vid2;
};

#define TB_I 782   // ceil(100000/128)
#define TB_U 391   // ceil(50000/128)
#define SC_B 733   // ceil(EALL/1024), 4 edges/thread

__global__ __launch_bounds__(256, 5) void transform(TArgs AI, TArgs AU, ScArgs S, char* __restrict__ ws) {
    int b = blockIdx.x;
    if (b >= TB_I + TB_U) {
        // ---- edge scatter (CSR records), 4 edges per thread ----
        int e0 = ((b - TB_I - TB_U) * 256 + threadIdx.x) * 4;
        if (e0 < EALL) {
            int* cursor = (int*)(ws + OFF_CURSOR);
            const int* bsum = (const int*)(ws + OFF_BSUM);
            int2* ord = (int2*)(ws + OFF_ORD);
            int4 u, c, d;
            if (e0 < E1N) {
                u = *(const int4*)(S.uid1 + e0);
                d = *(const int4*)(S.vid1 + e0);
                c = *(const int4*)(S.cnt1 + e0);
            } else {
                int ee = e0 - E1N;
                u = *(const int4*)(S.uid2 + ee);
                d = *(const int4*)(S.vid2 + ee);
                u.x += N_ITEM; u.y += N_ITEM; u.z += N_ITEM; u.w += N_ITEM;
                c = make_int4(-1, -1, -1, -1);
            }
            int us[4] = {u.x, u.y, u.z, u.w};
            int ds[4] = {d.x, d.y, d.z, d.w};
            int cs[4] = {c.x, c.y, c.z, c.w};
            #pragma unroll
            for (int j = 0; j < 4; j++) {
                int dst = ds[j];
                int pos = atomicAdd(&cursor[dst], 1) + bsum[dst >> 10];
                int2 rec; rec.x = us[j]; rec.y = cs[j];
                ord[pos] = rec;
            }
        }
        return;
    }
    const TArgs& A = (b < TB_I) ? AI : AU;
    int blk = (b < TB_I) ? b : b - TB_I;

    const unsigned short* wpack = (const unsigned short*)(ws + OFF_WPACK);
    const float* scaleb = (const float*)(ws + OFF_SCALE) + A.scaleOff;
    int tid = threadIdx.x, lane = tid & 63;
    int wv = tid >> 6;
    int l16 = lane & 15, quad = lane >> 4;
    int base = blk * 128 + wv * 32;

    // B-fragments: BN-applied feature rows (bf16), zero-padded beyond N
    bf16x8 bfr[2][4];
    #pragma unroll
    for (int kt = 0; kt < 4; kt++) {
        int c0 = kt * 32 + quad * 8;
        float4 sc0 = *(const float4*)(scaleb + c0);
        float4 sc1 = *(const float4*)(scaleb + c0 + 4);
        float4 bi0 = *(const float4*)(scaleb + 128 + c0);
        float4 bi1 = *(const float4*)(scaleb + 128 + c0 + 4);
        #pragma unroll
        for (int it = 0; it < 2; it++) {
            int gr = base + it * 16 + l16;
            bf16x8 f = {0, 0, 0, 0, 0, 0, 0, 0};
            if (gr < A.N) {
                const float* p = A.x + (size_t)gr * 128 + c0;
                float4 v0 = *(const float4*)p;
                float4 v1 = *(const float4*)(p + 4);
                f[0] = (short)f2bf(fmaf(v0.x, sc0.x, bi0.x));
                f[1] = (short)f2bf(fmaf(v0.y, sc0.y, bi0.y));
                f[2] = (short)f2bf(fmaf(v0.z, sc0.z, bi0.z));
                f[3] = (short)f2bf(fmaf(v0.w, sc0.w, bi0.w));
                f[4] = (short)f2bf(fmaf(v1.x, sc1.x, bi1.x));
                f[5] = (short)f2bf(fmaf(v1.y, sc1.y, bi1.y));
                f[6] = (short)f2bf(fmaf(v1.z, sc1.z, bi1.z));
                f[7] = (short)f2bf(fmaf(v1.w, sc1.w, bi1.w));
            }
            bfr[it][kt] = f;
        }
    }

    int gr0 = base + l16;          // it = 0 row
    int gr1 = base + 16 + l16;     // it = 1 row
    bool in0 = gr0 < A.N, in1 = gr1 < A.N;

    for (int m = 0; m < A.nmat; m++) {
        const unsigned short* wp = wpack + (size_t)A.wtIdx[m] * 16384;
        unsigned short* outp = A.out[m];
        const float* bias = (m == 0) ? A.bias0 : nullptr;
        #pragma unroll
        for (int nt = 0; nt < 8; nt++) {
            bf16x8 a4[4];
            #pragma unroll
            for (int kt = 0; kt < 4; kt++)
                a4[kt] = *(const bf16x8*)(wp + (size_t)((nt * 4 + kt) * 64 + lane) * 8);
            f32x4 acc0 = {0.f, 0.f, 0.f, 0.f};
            if (bias) {
                float4 bv = *(const float4*)(bias + nt * 16 + quad * 4);
                acc0[0] = bv.x; acc0[1] = bv.y; acc0[2] = bv.z; acc0[3] = bv.w;
            }
            f32x4 acc1 = acc0;
            #pragma unroll
            for (int kt = 0; kt < 4; kt++) {
                acc0 = __builtin_amdgcn_mfma_f32_16x16x32_bf16(a4[kt], bfr[0][kt], acc0, 0, 0, 0);
                acc1 = __builtin_amdgcn_mfma_f32_16x16x32_bf16(a4[kt], bfr[1][kt], acc1, 0, 0, 0);
            }
            ushort4 o0 = make_ushort4(f2bf(acc0[0]), f2bf(acc0[1]), f2bf(acc0[2]), f2bf(acc0[3]));
            ushort4 o1 = make_ushort4(f2bf(acc1[0]), f2bf(acc1[1]), f2bf(acc1[2]), f2bf(acc1[3]));
            int co = nt * 16 + quad * 4;
            if (in0) *(ushort4*)(outp + (size_t)gr0 * 128 + co) = o0;
            if (in1) *(ushort4*)(outp + (size_t)gr1 * 128 + co) = o1;
        }
    }
}

// ---------------- fused edge phase: wave per dst, 4 slots, ushort8 loads ---
// (R5/R8 byte-exact: 107.5 us measured, VGPR 40, no spill. The R7 pipeline
//  variant spilled to scratch (+196MB WRITE) -- do not re-add live state.)
__global__ __launch_bounds__(256, 6) void edge_agg(const float* __restrict__ ae1, const float* __restrict__ ae2,
                                                   char* __restrict__ ws) {
    const unsigned short* qc = (const unsigned short*)(ws + OFF_QC);
    const unsigned short* vc = (const unsigned short*)(ws + OFF_VC);
    const unsigned short* k1 = (const unsigned short*)(ws + OFF_K1);
    const unsigned short* k2 = (const unsigned short*)(ws + OFF_K2);
    const unsigned short* embb = (const unsigned short*)(ws + OFF_EMBB);
    const int* start = (const int*)(ws + OFF_START);
    const int* bsum  = (const int*)(ws + OFF_BSUM);
    const int2* ord = (const int2*)(ws + OFF_ORD);
    const float* M = (const float*)(ws + OFF_M);
    unsigned short* aggb = (unsigned short*)(ws + OFF_AGG);

    int tid = threadIdx.x;
    int lane = tid & 63;
    int slot = lane >> 4;     // 4 edge slots per wave
    int l = lane & 15;        // 16 lanes per slot
    int d0 = l << 3;          // 8 dims per lane
    int h = l >> 1;           // head (DH=16 => 2 lanes/head)
    int dst = blockIdx.x * 4 + (tid >> 6);
    if (dst >= N_ITEM) return;

    float mh = M[h];
    float ae1v[8], ae2v[8], k1v[8], k2v[8];
    {
        float4 t0 = *(const float4*)(ae1 + d0);
        float4 t1 = *(const float4*)(ae1 + d0 + 4);
        ae1v[0]=t0.x; ae1v[1]=t0.y; ae1v[2]=t0.z; ae1v[3]=t0.w;
        ae1v[4]=t1.x; ae1v[5]=t1.y; ae1v[6]=t1.z; ae1v[7]=t1.w;
        float4 t2 = *(const float4*)(ae2 + d0);
        float4 t3 = *(const float4*)(ae2 + d0 + 4);
        ae2v[0]=t2.x; ae2v[1]=t2.y; ae2v[2]=t2.z; ae2v[3]=t2.w;
        ae2v[4]=t3.x; ae2v[5]=t3.y; ae2v[6]=t3.z; ae2v[7]=t3.w;
        bf16x8 k1p = *(const bf16x8*)(k1 + (size_t)dst * 128 + d0);
        bf16x8 k2p = *(const bf16x8*)(k2 + (size_t)dst * 128 + d0);
        #pragma unroll
        for (int j = 0; j < 8; j++) {
            k1v[j] = bf2f((unsigned short)k1p[j]);
            k2v[j] = bf2f((unsigned short)k2p[j]);
        }
    }

    int beg = start[dst] + bsum[dst >> 10];
    int end = start[dst + 1] + bsum[(dst + 1) >> 10];
    float a[8] = {0.f, 0.f, 0.f, 0.f, 0.f, 0.f, 0.f, 0.f};
    float s = 0.f;

    int i = beg + slot;
    if (i < end) {
        int2 rec = ord[i];
        while (true) {
            int inext = i + 4;
            int ipf = (inext < end) ? inext : (end - 1);
            int2 recn = ord[ipf];                     // prefetch next record
            bool t1e = rec.y >= 0;
            bf16x8 qp = *(const bf16x8*)(qc + (size_t)rec.x * 128 + d0);
            bf16x8 vp = *(const bf16x8*)(vc + (size_t)rec.x * 128 + d0);
            bf16x8 ep = *(const bf16x8*)(embb + (size_t)(t1e ? rec.y : 0) * 128 + d0);
            float t = 0.f;
            #pragma unroll
            for (int j = 0; j < 8; j++) {
                float kv = t1e ? (k1v[j] + bf2f((unsigned short)ep[j])) : k2v[j];
                float x = bf2f((unsigned short)qp[j]) + kv;
                float sg = __builtin_amdgcn_rcpf(1.f + __expf(-x));
                t = fmaf(t1e ? ae1v[j] : ae2v[j], sg, t);
            }
            t += __shfl_xor(t, 1);            // head reduce (2 lanes)
            float ex = __expf(t - mh);
            s += ex;
            #pragma unroll
            for (int j = 0; j < 8; j++)
                a[j] = fmaf(ex, bf2f((unsigned short)vp[j]), a[j]);
            if (inext >= end) break;
            i = inext; rec = recn;
        }
    }
    // combine the four edge slots
    s += __shfl_xor(s, 16);
    s += __shfl_xor(s, 32);
    #pragma unroll
    for (int j = 0; j < 8; j++) {
        a[j] += __shfl_xor(a[j], 16);
        a[j] += __shfl_xor(a[j], 32);
    }
    if (slot == 0) {
        float inv = (s > 0.f) ? __builtin_amdgcn_rcpf(s) : 0.f;
        bf16x8 o;
        #pragma unroll
        for (int j = 0; j < 8; j++)
            o[j] = (short)f2bf(a[j] * inv);
        *(bf16x8*)(aggb + (size_t)dst * 128 + d0) = o;   // 16 lanes x 16B = 256B/row
    }
}

// ---------------- final: relu(agg @ Wagg.T + b + selfterm), DIRECT stores --
// (R8 byte-exact: no LDS, nt-outer, 4 MFMA chains.)
__global__ __launch_bounds__(256) void final_mfma(const float* __restrict__ b_agg,
                                                  float* __restrict__ out, char* __restrict__ ws) {
    const unsigned short* aggb = (const unsigned short*)(ws + OFF_AGG);
    const unsigned short* selft = (const unsigned short*)(ws + OFF_SELF);
    const unsigned short* wp = (const unsigned short*)(ws + OFF_WPACK) + 7ull * 16384;
    int tid = threadIdx.x, lane = tid & 63, wv = tid >> 6;
    int l16 = lane & 15, quad = lane >> 4;
    int base = blockIdx.x * 256 + wv * 64;

    // B-fragments from agg rows: direct bf16x8 loads (agg stored bf16)
    bf16x8 bfr[4][4];
    #pragma unroll
    for (int it = 0; it < 4; it++) {
        int gr = base + it * 16 + l16;
        #pragma unroll
        for (int kt = 0; kt < 4; kt++) {
            bf16x8 f = {0, 0, 0, 0, 0, 0, 0, 0};
            if (gr < N_ITEM)
                f = *(const bf16x8*)(aggb + (size_t)gr * 128 + kt * 32 + quad * 8);
            bfr[it][kt] = f;
        }
    }

    #pragma unroll
    for (int nt = 0; nt < 8; nt++) {
        bf16x8 a4[4];
        #pragma unroll
        for (int kt = 0; kt < 4; kt++)
            a4[kt] = *(const bf16x8*)(wp + (size_t)((nt * 4 + kt) * 64 + lane) * 8);
        float4 bv = *(const float4*)(b_agg + nt * 16 + quad * 4);
        f32x4 acc0 = {bv.x, bv.y, bv.z, bv.w};
        f32x4 acc1 = acc0, acc2 = acc0, acc3 = acc0;
        #pragma unroll
        for (int kt = 0; kt < 4; kt++) {
            acc0 = __builtin_amdgcn_mfma_f32_16x16x32_bf16(a4[kt], bfr[0][kt], acc0, 0, 0, 0);
            acc1 = __builtin_amdgcn_mfma_f32_16x16x32_bf16(a4[kt], bfr[1][kt], acc1, 0, 0, 0);
            acc2 = __builtin_amdgcn_mfma_f32_16x16x32_bf16(a4[kt], bfr[2][kt], acc2, 0, 0, 0);
            acc3 = __builtin_amdgcn_mfma_f32_16x16x32_bf16(a4[kt], bfr[3][kt], acc3, 0, 0, 0);
        }
        int co = nt * 16 + quad * 4;
        #pragma unroll
        for (int it = 0; it < 4; it++) {
            f32x4 acc = (it == 0) ? acc0 : (it == 1) ? acc1 : (it == 2) ? acc2 : acc3;
            int gr = base + it * 16 + l16;
            if (gr < N_ITEM) {
                size_t idx = (size_t)gr * 128 + co;
                ushort4 sf = *(const ushort4*)(selft + idx);
                float4 o;
                o.x = fmaxf(acc[0] + bf2f(sf.x), 0.f);
                o.y = fmaxf(acc[1] + bf2f(sf.y), 0.f);
                o.z = fmaxf(acc[2] + bf2f(sf.z), 0.f);
                o.w = fmaxf(acc[3] + bf2f(sf.w), 0.f);
                *(float4*)(out + idx) = o;
            }
        }
    }
}

// ---------------- host ----------------
extern "C" void kernel_launch(void* const* d_in, const int* in_sizes, int n_in,
                              void* d_out, int out_size, void* d_ws, size_t ws_size,
                              hipStream_t stream) {
    char* ws = (char*)d_ws;

    const float* ft_item = (const float*)d_in[0];
    const float* ft_user = (const float*)d_in[1];
    const float* bng_i = (const float*)d_in[2];
    const float* bnb_i = (const float*)d_in[3];
    const float* bng_u = (const float*)d_in[4];
    const float* bnb_u = (const float*)d_in[5];
    const float* Wq1 = (const float*)d_in[6];
    const float* bq1 = (const float*)d_in[7];
    const float* Wk1 = (const float*)d_in[8];
    const float* Wv1 = (const float*)d_in[9];
    const float* ae1 = (const float*)d_in[10];
    const float* emb = (const float*)d_in[11];
    const float* Wq2 = (const float*)d_in[12];
    const float* bq2 = (const float*)d_in[13];
    const float* Wk2 = (const float*)d_in[14];
    const float* Wv2 = (const float*)d_in[15];
    const float* ae2 = (const float*)d_in[16];
    const float* W_agg = (const float*)d_in[17];
    const float* b_agg = (const float*)d_in[18];
    const float* W_self = (const float*)d_in[19];
    const int* uid1 = (const int*)d_in[20];
    const int* vid1 = (const int*)d_in[21];
    const int* cnt1 = (const int*)d_in[22];
    const int* uid2 = (const int*)d_in[23];
    const int* vid2 = (const int*)d_in[24];
    float* out = (float*)d_out;

    // single memset: stats (2KB) + hist + scan ticket (adjacent)
    hipMemsetAsync(ws + OFF_STATS, 0, 2048 + (size_t)NPAD * 4 + 64, stream);

    // 1. prologue: BN stats + dst histogram + pack weights + emb->bf16
    ProArgs pa;
    pa.w[0] = Wq1; pa.w[1] = Wk1; pa.w[2] = Wv1; pa.w[3] = Wk2;
    pa.w[4] = W_self; pa.w[5] = Wq2; pa.w[6] = Wv2; pa.w[7] = W_agg;
    pa.ft_item = ft_item; pa.ft_user = ft_user; pa.emb = emb;
    pa.vid1 = vid1; pa.vid2 = vid2;
    prologue<<<PRO_STAT + PRO_HIST + PRO_PACK + PRO_EMB, 256, 0, stream>>>(pa, ws);

    // 2+3. fused chunk scans + top-scan (ticket) + BN finalize (block 98)
    scan_fused<<<99, 1024, 0, stream>>>(bng_i, bnb_i, bng_u, bnb_u, ae1, ae2, ws);

    // 4+5. all 7 node-transform GEMMs + co-scheduled edge scatter (tail)
    TArgs ti, tu;
    ti.x = ft_item; ti.bias0 = bq1; ti.N = N_ITEM; ti.scaleOff = 0; ti.nmat = 5;
    ti.wtIdx[0] = 0; ti.wtIdx[1] = 1; ti.wtIdx[2] = 2; ti.wtIdx[3] = 3; ti.wtIdx[4] = 4;
    unsigned short* QC = (unsigned short*)(ws + OFF_QC);
    unsigned short* VC = (unsigned short*)(ws + OFF_VC);
    ti.out[0] = QC;
    ti.out[1] = (unsigned short*)(ws + OFF_K1);
    ti.out[2] = VC;
    ti.out[3] = (unsigned short*)(ws + OFF_K2);
    ti.out[4] = (unsigned short*)(ws + OFF_SELF);
    tu.x = ft_user; tu.bias0 = bq2; tu.N = N_USER; tu.scaleOff = 256; tu.nmat = 2;
    tu.wtIdx[0] = 5; tu.wtIdx[1] = 6; tu.wtIdx[2] = 0; tu.wtIdx[3] = 0; tu.wtIdx[4] = 0;
    tu.out[0] = QC + (size_t)N_ITEM * 128;
    tu.out[1] = VC + (size_t)N_ITEM * 128;
    tu.out[2] = tu.out[3] = tu.out[4] = tu.out[0];
    ScArgs sa;
    sa.uid1 = uid1; sa.vid1 = vid1; sa.cnt1 = cnt1; sa.uid2 = uid2; sa.vid2 = vid2;
    transform<<<TB_I + TB_U + SC_B, 256, 0, stream>>>(ti, tu, sa, ws);

    // 6. fused edge softmax+aggregate (4 slots/wave, 16B loads)
    edge_agg<<<(N_ITEM + 3) / 4, 256, 0, stream>>>(ae1, ae2, ws);

    // 7. final GEMM + self + relu (direct stores, no LDS)
    final_mfma<<<(N_ITEM + 255) / 256, 256, 0, stream>>>(b_agg, out, ws);
}

// Round 11
// 421.767 us; speedup vs baseline: 1.1772x; 1.0079x over previous
//
#include <hip/hip_runtime.h>
#include <hip/hip_bf16.h>

#define N_ITEM 100000
#define N_USER 50000
#define N_ALL  150000
#define E1N 500000
#define E2N 250000
#define EALL (E1N + E2N)
#define NPAD 100352          // 98 * 1024, >= N_ITEM+1

// ---------------- workspace layout (bytes) ----------------
static constexpr size_t OFF_STATS = 0;                       // 512 f32 (zeroed)
static constexpr size_t OFF_HIST  = 2048;                    // NPAD ints (zeroed)
static constexpr size_t OFF_CNT   = OFF_HIST + (size_t)NPAD * 4;       // 64 B (zeroed): scan ticket
static constexpr size_t OFF_SCALE = OFF_CNT + 64;                      // 512 f32
static constexpr size_t OFF_M     = OFF_SCALE + 2048;                  // 8 f32
static constexpr size_t OFF_EMBB  = OFF_M + 64;                        // bf16 emb [51,128] = 13056 B
static constexpr size_t OFF_WPACK = OFF_EMBB + 13312;        // 8 matrices bf16 frag-packed
static constexpr size_t OFF_QC    = OFF_WPACK + 8ull * 32768ull;       // bf16 [N_ALL,128] q1|q2
static constexpr size_t OFF_VC    = OFF_QC + (size_t)N_ALL * 256;      // bf16 v1|v2
static constexpr size_t OFF_K1    = OFF_VC + (size_t)N_ALL * 256;
static constexpr size_t OFF_K2    = OFF_K1 + (size_t)N_ITEM * 256;
static constexpr size_t OFF_SELF  = OFF_K2 + (size_t)N_ITEM * 256;
static constexpr size_t OFF_START = OFF_SELF + (size_t)N_ITEM * 256;   // NPAD ints (within-chunk exclusive)
static constexpr size_t OFF_CURSOR= OFF_START + (size_t)NPAD * 4;      // NPAD ints
static constexpr size_t OFF_BSUM  = OFF_CURSOR + (size_t)NPAD * 4;     // 128 ints
static constexpr size_t OFF_ORD   = OFF_BSUM + 1024;                   // EALL int2
static constexpr size_t OFF_AGG   = OFF_ORD + (size_t)EALL * 8 + 128;  // bf16 [N_ITEM,128]

// ---------------- helpers ----------------
__device__ __forceinline__ float bf2f(unsigned short u) {
    return __uint_as_float(((unsigned)u) << 16);
}
__device__ __forceinline__ unsigned short f2bf(float f) {
    unsigned u = __float_as_uint(f);
    u += 0x7fffu + ((u >> 16) & 1u);   // round-to-nearest-even
    return (unsigned short)(u >> 16);
}

typedef __attribute__((ext_vector_type(8))) short bf16x8;
typedef __attribute__((ext_vector_type(4))) float f32x4;

// ---------------- prologue: bn_stats + edge_hist + pack_w + emb->bf16 ------
struct ProArgs {
    const float* w[8];
    const float* ft_item;
    const float* ft_user;
    const float* emb;
    const int* vid1;
    const int* vid2;
};
#define PRO_STAT 768    // 512 item + 256 user, float4 loads, 8 rows/blk/iter
#define PRO_HIST 733    // ceil(EALL/1024), 4 edges/thread
#define PRO_PACK 64
#define PRO_EMB  7      // 51*128/4 = 1632 threads

__global__ __launch_bounds__(256) void prologue(ProArgs A, char* __restrict__ ws) {
    __shared__ float r1[4][128], r2[4][128];
    int b = blockIdx.x, tid = threadIdx.x;
    if (b < PRO_STAT) {
        // BN stats: vectorized float4, 4 loads in flight per wave, LDS reduce.
        int type = (b >= 512) ? 1 : 0;
        int xb = type ? (b - 512) : b;
        int nb = type ? 256 : 512;
        const float* x = type ? A.ft_user : A.ft_item;
        int N = type ? N_USER : N_ITEM;
        float* sum = (float*)(ws + OFF_STATS) + type * 256;
        float* sq  = sum + 128;
        int c4 = (tid & 31) * 4;        // 4 columns per lane
        int rg = tid >> 5;              // row group 0..7
        int step = nb * 8;
        float s0 = 0.f, s1 = 0.f, s2 = 0.f, s3 = 0.f;
        float q0 = 0.f, q1 = 0.f, q2 = 0.f, q3 = 0.f;
        #pragma unroll 4
        for (int r = xb * 8 + rg; r < N; r += step) {
            float4 v = *(const float4*)(x + (size_t)r * 128 + c4);
            s0 += v.x; s1 += v.y; s2 += v.z; s3 += v.w;
            q0 = fmaf(v.x, v.x, q0); q1 = fmaf(v.y, v.y, q1);
            q2 = fmaf(v.z, v.z, q2); q3 = fmaf(v.w, v.w, q3);
        }
        // lane l and l+32 have the same columns (rows r, r+1): combine
        s0 += __shfl_xor(s0, 32); s1 += __shfl_xor(s1, 32);
        s2 += __shfl_xor(s2, 32); s3 += __shfl_xor(s3, 32);
        q0 += __shfl_xor(q0, 32); q1 += __shfl_xor(q1, 32);
        q2 += __shfl_xor(q2, 32); q3 += __shfl_xor(q3, 32);
        int wv = tid >> 6;
        if ((tid & 63) < 32) {
            *(float4*)&r1[wv][c4] = make_float4(s0, s1, s2, s3);
            *(float4*)&r2[wv][c4] = make_float4(q0, q1, q2, q3);
        }
        __syncthreads();
        if (tid < 128) {
            float a  = r1[0][tid] + r1[1][tid] + r1[2][tid] + r1[3][tid];
            float bb = r2[0][tid] + r2[1][tid] + r2[2][tid] + r2[3][tid];
            atomicAdd(&sum[tid], a);
            atomicAdd(&sq[tid], bb);
        }
    } else if (b < PRO_STAT + PRO_HIST) {
        // dst histogram, 4 edges/thread (E1N, EALL divisible by 4)
        int e4 = ((b - PRO_STAT) * 256 + tid) * 4;
        if (e4 < EALL) {
            int* hist = (int*)(ws + OFF_HIST);
            int4 v;
            if (e4 < E1N) v = *(const int4*)(A.vid1 + e4);
            else          v = *(const int4*)(A.vid2 + (e4 - E1N));
            atomicAdd(&hist[v.x], 1);
            atomicAdd(&hist[v.y], 1);
            atomicAdd(&hist[v.z], 1);
            atomicAdd(&hist[v.w], 1);
        }
    } else if (b < PRO_STAT + PRO_HIST + PRO_PACK) {
        // pack weights into MFMA fragment order:
        // frag(m,t,kt,lane) = W[n=t*16+(lane&15)][k=kt*32+(lane>>4)*8 + j], j=0..7
        unsigned short* dst = (unsigned short*)(ws + OFF_WPACK);
        int gid = (b - PRO_STAT - PRO_HIST) * 256 + tid;
        int m = gid >> 11, rem = gid & 2047;
        int t = rem >> 8, kt = (rem >> 6) & 3, lane = rem & 63;
        int n = t * 16 + (lane & 15);
        int k0 = kt * 32 + (lane >> 4) * 8;
        const float* wrow = A.w[m] + n * 128 + k0;
        float4 w0 = *(const float4*)wrow;
        float4 w1 = *(const float4*)(wrow + 4);
        ushort4 o0 = make_ushort4(f2bf(w0.x), f2bf(w0.y), f2bf(w0.z), f2bf(w0.w));
        ushort4 o1 = make_ushort4(f2bf(w1.x), f2bf(w1.y), f2bf(w1.z), f2bf(w1.w));
        *(ushort4*)(dst + (size_t)gid * 8)     = o0;
        *(ushort4*)(dst + (size_t)gid * 8 + 4) = o1;
    } else {
        int gid = (b - PRO_STAT - PRO_HIST - PRO_PACK) * 256 + tid;   // 4 elems/thread
        if (gid * 4 < 51 * 128) {
            float4 v = *(const float4*)(A.emb + gid * 4);
            ushort4 o = make_ushort4(f2bf(v.x), f2bf(v.y), f2bf(v.z), f2bf(v.w));
            *(ushort4*)((unsigned short*)(ws + OFF_EMBB) + gid * 4) = o;
        }
    }
}

// ---------------- scan_fused: chunk scans + top-scan (last block) ----------
// Blocks 0..97: per-1024-chunk exclusive scan; publish chunk sum; ticket.
// Last chunk block through the ticket does the 98-entry top-scan.
// Block 98: independent BN-finalize + per-head shift M.
__global__ __launch_bounds__(1024) void scan_fused(const float* __restrict__ g_i, const float* __restrict__ b_i,
                                                   const float* __restrict__ g_u, const float* __restrict__ b_u,
                                                   const float* __restrict__ ae1, const float* __restrict__ ae2,
                                                   char* __restrict__ ws) {
    __shared__ int sd[1024];
    __shared__ int lastBlk;
    int t = threadIdx.x;
    int b = blockIdx.x;
    if (b == 98) {
        // ---- BN finalize (depends only on prologue stats) ----
        if (t < 256) {
            const float* stats = (const float*)(ws + OFF_STATS);
            float* scale = (float*)(ws + OFF_SCALE);
            float* M     = (float*)(ws + OFF_M);
            int type = t >> 7, c = t & 127;
            float N = type ? (float)N_USER : (float)N_ITEM;
            float su = stats[type * 256 + c];
            float sq = stats[type * 256 + 128 + c];
            float mu = su / N;
            float var = sq / N - mu * mu;
            float rstd = rsqrtf(var + 1e-5f);
            float g = type ? g_u[c] : g_i[c];
            float bb = type ? b_u[c] : b_i[c];
            scale[type * 256 + c]       = g * rstd;
            scale[type * 256 + 128 + c] = bb - mu * g * rstd;
            if (t < 8) {
                float m1 = 0.f, m2 = 0.f;
                for (int j = 0; j < 16; j++) {
                    m1 += fmaxf(ae1[t * 16 + j], 0.f);
                    m2 += fmaxf(ae2[t * 16 + j], 0.f);
                }
                M[t] = fmaxf(m1, m2);   // uniform per-head shift, both etypes
            }
        }
        return;
    }
    const int* hist = (const int*)(ws + OFF_HIST);
    int* start  = (int*)(ws + OFF_START);
    int* cursor = (int*)(ws + OFF_CURSOR);
    int* bsum   = (int*)(ws + OFF_BSUM);
    int* cnt    = (int*)(ws + OFF_CNT);
    int gid = b * 1024 + t;
    int v = hist[gid];
    sd[t] = v;
    __syncthreads();
    #pragma unroll
    for (int off = 1; off < 1024; off <<= 1) {
        int x = (t >= off) ? sd[t - off] : 0;
        __syncthreads();
        sd[t] += x;
        __syncthreads();
    }
    int ex = sd[t] - v;        // exclusive within chunk
    start[gid] = ex;
    cursor[gid] = ex;
    if (t == 1023) {
        bsum[b] = sd[t];
        __threadfence();       // publish chunk sum device-wide
    }
    __syncthreads();
    if (t == 0) lastBlk = (atomicAdd(cnt, 1) == 97) ? 1 : 0;
    __syncthreads();
    if (lastBlk) {
        __threadfence();       // acquire: all bsum writes visible
        int v2 = 0;
        if (t < 128) { v2 = (t < 98) ? bsum[t] : 0; sd[t] = v2; }
        __syncthreads();
        #pragma unroll
        for (int off = 1; off < 128; off <<= 1) {
            int x = 0;
            if (t < 128 && t >= off) x = sd[t - off];
            __syncthreads();
            if (t < 128) sd[t] += x;
            __syncthreads();
        }
        if (t < 98) bsum[t] = sd[t] - v2;   // exclusive chunk offsets
    }
}

// ---------------- transform: 32 rows/wave, DIRECT MFMA stores (no LDS) -----
// (R4/R5/R8 code+bound byte-exact: VGPR 36, no LDS, no spill, ~110 us.
//  DO NOT change the launch bound: 6 and 8 both flipped codegen to spill.)
struct TArgs {
    const float* x;              // raw f32 features
    const float* bias0;          // bias for matrix 0 (q), may be null
    int N;
    int scaleOff;                // 0 item, 256 user
    int nmat;
    int wtIdx[5];
    unsigned short* out[5];
};
struct ScArgs {
    const int* uid1; const int* vid1; const int* cnt1;
    const int* uid2; const int* vid2;
};

#define TB_I 782   // ceil(100000/128)
#define TB_U 391   // ceil(50000/128)
#define SC_B 733   // ceil(EALL/1024), 4 edges/thread

__global__ __launch_bounds__(256, 5) void transform(TArgs AI, TArgs AU, ScArgs S, char* __restrict__ ws) {
    int b = blockIdx.x;
    if (b >= TB_I + TB_U) {
        // ---- edge scatter (CSR records), 4 edges per thread ----
        int e0 = ((b - TB_I - TB_U) * 256 + threadIdx.x) * 4;
        if (e0 < EALL) {
            int* cursor = (int*)(ws + OFF_CURSOR);
            const int* bsum = (const int*)(ws + OFF_BSUM);
            int2* ord = (int2*)(ws + OFF_ORD);
            int4 u, c, d;
            if (e0 < E1N) {
                u = *(const int4*)(S.uid1 + e0);
                d = *(const int4*)(S.vid1 + e0);
                c = *(const int4*)(S.cnt1 + e0);
            } else {
                int ee = e0 - E1N;
                u = *(const int4*)(S.uid2 + ee);
                d = *(const int4*)(S.vid2 + ee);
                u.x += N_ITEM; u.y += N_ITEM; u.z += N_ITEM; u.w += N_ITEM;
                c = make_int4(-1, -1, -1, -1);
            }
            int us[4] = {u.x, u.y, u.z, u.w};
            int ds[4] = {d.x, d.y, d.z, d.w};
            int cs[4] = {c.x, c.y, c.z, c.w};
            #pragma unroll
            for (int j = 0; j < 4; j++) {
                int dst = ds[j];
                int pos = atomicAdd(&cursor[dst], 1) + bsum[dst >> 10];
                int2 rec; rec.x = us[j]; rec.y = cs[j];
                ord[pos] = rec;
            }
        }
        return;
    }
    const TArgs& A = (b < TB_I) ? AI : AU;
    int blk = (b < TB_I) ? b : b - TB_I;

    const unsigned short* wpack = (const unsigned short*)(ws + OFF_WPACK);
    const float* scaleb = (const float*)(ws + OFF_SCALE) + A.scaleOff;
    int tid = threadIdx.x, lane = tid & 63;
    int wv = tid >> 6;
    int l16 = lane & 15, quad = lane >> 4;
    int base = blk * 128 + wv * 32;

    // B-fragments: BN-applied feature rows (bf16), zero-padded beyond N
    bf16x8 bfr[2][4];
    #pragma unroll
    for (int kt = 0; kt < 4; kt++) {
        int c0 = kt * 32 + quad * 8;
        float4 sc0 = *(const float4*)(scaleb + c0);
        float4 sc1 = *(const float4*)(scaleb + c0 + 4);
        float4 bi0 = *(const float4*)(scaleb + 128 + c0);
        float4 bi1 = *(const float4*)(scaleb + 128 + c0 + 4);
        #pragma unroll
        for (int it = 0; it < 2; it++) {
            int gr = base + it * 16 + l16;
            bf16x8 f = {0, 0, 0, 0, 0, 0, 0, 0};
            if (gr < A.N) {
                const float* p = A.x + (size_t)gr * 128 + c0;
                float4 v0 = *(const float4*)p;
                float4 v1 = *(const float4*)(p + 4);
                f[0] = (short)f2bf(fmaf(v0.x, sc0.x, bi0.x));
                f[1] = (short)f2bf(fmaf(v0.y, sc0.y, bi0.y));
                f[2] = (short)f2bf(fmaf(v0.z, sc0.z, bi0.z));
                f[3] = (short)f2bf(fmaf(v0.w, sc0.w, bi0.w));
                f[4] = (short)f2bf(fmaf(v1.x, sc1.x, bi1.x));
                f[5] = (short)f2bf(fmaf(v1.y, sc1.y, bi1.y));
                f[6] = (short)f2bf(fmaf(v1.z, sc1.z, bi1.z));
                f[7] = (short)f2bf(fmaf(v1.w, sc1.w, bi1.w));
            }
            bfr[it][kt] = f;
        }
    }

    int gr0 = base + l16;          // it = 0 row
    int gr1 = base + 16 + l16;     // it = 1 row
    bool in0 = gr0 < A.N, in1 = gr1 < A.N;

    for (int m = 0; m < A.nmat; m++) {
        const unsigned short* wp = wpack + (size_t)A.wtIdx[m] * 16384;
        unsigned short* outp = A.out[m];
        const float* bias = (m == 0) ? A.bias0 : nullptr;
        #pragma unroll
        for (int nt = 0; nt < 8; nt++) {
            bf16x8 a4[4];
            #pragma unroll
            for (int kt = 0; kt < 4; kt++)
                a4[kt] = *(const bf16x8*)(wp + (size_t)((nt * 4 + kt) * 64 + lane) * 8);
            f32x4 acc0 = {0.f, 0.f, 0.f, 0.f};
            if (bias) {
                float4 bv = *(const float4*)(bias + nt * 16 + quad * 4);
                acc0[0] = bv.x; acc0[1] = bv.y; acc0[2] = bv.z; acc0[3] = bv.w;
            }
            f32x4 acc1 = acc0;
            #pragma unroll
            for (int kt = 0; kt < 4; kt++) {
                acc0 = __builtin_amdgcn_mfma_f32_16x16x32_bf16(a4[kt], bfr[0][kt], acc0, 0, 0, 0);
                acc1 = __builtin_amdgcn_mfma_f32_16x16x32_bf16(a4[kt], bfr[1][kt], acc1, 0, 0, 0);
            }
            ushort4 o0 = make_ushort4(f2bf(acc0[0]), f2bf(acc0[1]), f2bf(acc0[2]), f2bf(acc0[3]));
            ushort4 o1 = make_ushort4(f2bf(acc1[0]), f2bf(acc1[1]), f2bf(acc1[2]), f2bf(acc1[3]));
            int co = nt * 16 + quad * 4;
            if (in0) *(ushort4*)(outp + (size_t)gr0 * 128 + co) = o0;
            if (in1) *(ushort4*)(outp + (size_t)gr1 * 128 + co) = o1;
        }
    }
}

// ---------------- fused edge phase: wave per dst, 4 slots, ushort8 loads ---
// (R5/R8 byte-exact: 107.5 us measured, VGPR 40, no spill. The R7 pipeline
//  variant spilled to scratch (+196MB WRITE) -- do not re-add live state.)
__global__ __launch_bounds__(256, 6) void edge_agg(const float* __restrict__ ae1, const float* __restrict__ ae2,
                                                   char* __restrict__ ws) {
    const unsigned short* qc = (const unsigned short*)(ws + OFF_QC);
    const unsigned short* vc = (const unsigned short*)(ws + OFF_VC);
    const unsigned short* k1 = (const unsigned short*)(ws + OFF_K1);
    const unsigned short* k2 = (const unsigned short*)(ws + OFF_K2);
    const unsigned short* embb = (const unsigned short*)(ws + OFF_EMBB);
    const int* start = (const int*)(ws + OFF_START);
    const int* bsum  = (const int*)(ws + OFF_BSUM);
    const int2* ord = (const int2*)(ws + OFF_ORD);
    const float* M = (const float*)(ws + OFF_M);
    unsigned short* aggb = (unsigned short*)(ws + OFF_AGG);

    int tid = threadIdx.x;
    int lane = tid & 63;
    int slot = lane >> 4;     // 4 edge slots per wave
    int l = lane & 15;        // 16 lanes per slot
    int d0 = l << 3;          // 8 dims per lane
    int h = l >> 1;           // head (DH=16 => 2 lanes/head)
    int dst = blockIdx.x * 4 + (tid >> 6);
    if (dst >= N_ITEM) return;

    float mh = M[h];
    float ae1v[8], ae2v[8], k1v[8], k2v[8];
    {
        float4 t0 = *(const float4*)(ae1 + d0);
        float4 t1 = *(const float4*)(ae1 + d0 + 4);
        ae1v[0]=t0.x; ae1v[1]=t0.y; ae1v[2]=t0.z; ae1v[3]=t0.w;
        ae1v[4]=t1.x; ae1v[5]=t1.y; ae1v[6]=t1.z; ae1v[7]=t1.w;
        float4 t2 = *(const float4*)(ae2 + d0);
        float4 t3 = *(const float4*)(ae2 + d0 + 4);
        ae2v[0]=t2.x; ae2v[1]=t2.y; ae2v[2]=t2.z; ae2v[3]=t2.w;
        ae2v[4]=t3.x; ae2v[5]=t3.y; ae2v[6]=t3.z; ae2v[7]=t3.w;
        bf16x8 k1p = *(const bf16x8*)(k1 + (size_t)dst * 128 + d0);
        bf16x8 k2p = *(const bf16x8*)(k2 + (size_t)dst * 128 + d0);
        #pragma unroll
        for (int j = 0; j < 8; j++) {
            k1v[j] = bf2f((unsigned short)k1p[j]);
            k2v[j] = bf2f((unsigned short)k2p[j]);
        }
    }

    int beg = start[dst] + bsum[dst >> 10];
    int end = start[dst + 1] + bsum[(dst + 1) >> 10];
    float a[8] = {0.f, 0.f, 0.f, 0.f, 0.f, 0.f, 0.f, 0.f};
    float s = 0.f;

    int i = beg + slot;
    if (i < end) {
        int2 rec = ord[i];
        while (true) {
            int inext = i + 4;
            int ipf = (inext < end) ? inext : (end - 1);
            int2 recn = ord[ipf];                     // prefetch next record
            bool t1e = rec.y >= 0;
            bf16x8 qp = *(const bf16x8*)(qc + (size_t)rec.x * 128 + d0);
            bf16x8 vp = *(const bf16x8*)(vc + (size_t)rec.x * 128 + d0);
            bf16x8 ep = *(const bf16x8*)(embb + (size_t)(t1e ? rec.y : 0) * 128 + d0);
            float t = 0.f;
            #pragma unroll
            for (int j = 0; j < 8; j++) {
                float kv = t1e ? (k1v[j] + bf2f((unsigned short)ep[j])) : k2v[j];
                float x = bf2f((unsigned short)qp[j]) + kv;
                float sg = __builtin_amdgcn_rcpf(1.f + __expf(-x));
                t = fmaf(t1e ? ae1v[j] : ae2v[j], sg, t);
            }
            t += __shfl_xor(t, 1);            // head reduce (2 lanes)
            float ex = __expf(t - mh);
            s += ex;
            #pragma unroll
            for (int j = 0; j < 8; j++)
                a[j] = fmaf(ex, bf2f((unsigned short)vp[j]), a[j]);
            if (inext >= end) break;
            i = inext; rec = recn;
        }
    }
    // combine the four edge slots
    s += __shfl_xor(s, 16);
    s += __shfl_xor(s, 32);
    #pragma unroll
    for (int j = 0; j < 8; j++) {
        a[j] += __shfl_xor(a[j], 16);
        a[j] += __shfl_xor(a[j], 32);
    }
    if (slot == 0) {
        float inv = (s > 0.f) ? __builtin_amdgcn_rcpf(s) : 0.f;
        bf16x8 o;
        #pragma unroll
        for (int j = 0; j < 8; j++)
            o[j] = (short)f2bf(a[j] * inv);
        *(bf16x8*)(aggb + (size_t)dst * 128 + d0) = o;   // 16 lanes x 16B = 256B/row
    }
}

// ---------------- final: relu(agg @ Wagg.T + b + selfterm), DIRECT stores --
// 128 rows/block (782 blocks): halves per-thread fragment footprint and
// serial L3-latency load chain; doubles resident waves (6 -> ~12/CU).
// Mirrors the transform's proven no-spill shape (bfr[2][4], 2 MFMA chains).
__global__ __launch_bounds__(256) void final_mfma(const float* __restrict__ b_agg,
                                                  float* __restrict__ out, char* __restrict__ ws) {
    const unsigned short* aggb = (const unsigned short*)(ws + OFF_AGG);
    const unsigned short* selft = (const unsigned short*)(ws + OFF_SELF);
    const unsigned short* wp = (const unsigned short*)(ws + OFF_WPACK) + 7ull * 16384;
    int tid = threadIdx.x, lane = tid & 63, wv = tid >> 6;
    int l16 = lane & 15, quad = lane >> 4;
    int base = blockIdx.x * 128 + wv * 32;

    // B-fragments from agg rows: direct bf16x8 loads (agg stored bf16)
    bf16x8 bfr[2][4];
    #pragma unroll
    for (int it = 0; it < 2; it++) {
        int gr = base + it * 16 + l16;
        #pragma unroll
        for (int kt = 0; kt < 4; kt++) {
            bf16x8 f = {0, 0, 0, 0, 0, 0, 0, 0};
            if (gr < N_ITEM)
                f = *(const bf16x8*)(aggb + (size_t)gr * 128 + kt * 32 + quad * 8);
            bfr[it][kt] = f;
        }
    }

    int gr0 = base + l16;          // it = 0 row
    int gr1 = base + 16 + l16;     // it = 1 row
    bool in0 = gr0 < N_ITEM, in1 = gr1 < N_ITEM;

    #pragma unroll
    for (int nt = 0; nt < 8; nt++) {
        bf16x8 a4[4];
        #pragma unroll
        for (int kt = 0; kt < 4; kt++)
            a4[kt] = *(const bf16x8*)(wp + (size_t)((nt * 4 + kt) * 64 + lane) * 8);
        float4 bv = *(const float4*)(b_agg + nt * 16 + quad * 4);
        f32x4 acc0 = {bv.x, bv.y, bv.z, bv.w};
        f32x4 acc1 = acc0;
        #pragma unroll
        for (int kt = 0; kt < 4; kt++) {
            acc0 = __builtin_amdgcn_mfma_f32_16x16x32_bf16(a4[kt], bfr[0][kt], acc0, 0, 0, 0);
            acc1 = __builtin_amdgcn_mfma_f32_16x16x32_bf16(a4[kt], bfr[1][kt], acc1, 0, 0, 0);
        }
        int co = nt * 16 + quad * 4;
        if (in0) {
            size_t idx = (size_t)gr0 * 128 + co;
            ushort4 sf = *(const ushort4*)(selft + idx);
            float4 o;
            o.x = fmaxf(acc0[0] + bf2f(sf.x), 0.f);
            o.y = fmaxf(acc0[1] + bf2f(sf.y), 0.f);
            o.z = fmaxf(acc0[2] + bf2f(sf.z), 0.f);
            o.w = fmaxf(acc0[3] + bf2f(sf.w), 0.f);
            *(float4*)(out + idx) = o;
        }
        if (in1) {
            size_t idx = (size_t)gr1 * 128 + co;
            ushort4 sf = *(const ushort4*)(selft + idx);
            float4 o;
            o.x = fmaxf(acc1[0] + bf2f(sf.x), 0.f);
            o.y = fmaxf(acc1[1] + bf2f(sf.y), 0.f);
            o.z = fmaxf(acc1[2] + bf2f(sf.z), 0.f);
            o.w = fmaxf(acc1[3] + bf2f(sf.w), 0.f);
            *(float4*)(out + idx) = o;
        }
    }
}

// ---------------- host ----------------
extern "C" void kernel_launch(void* const* d_in, const int* in_sizes, int n_in,
                              void* d_out, int out_size, void* d_ws, size_t ws_size,
                              hipStream_t stream) {
    char* ws = (char*)d_ws;

    const float* ft_item = (const float*)d_in[0];
    const float* ft_user = (const float*)d_in[1];
    const float* bng_i = (const float*)d_in[2];
    const float* bnb_i = (const float*)d_in[3];
    const float* bng_u = (const float*)d_in[4];
    const float* bnb_u = (const float*)d_in[5];
    const float* Wq1 = (const float*)d_in[6];
    const float* bq1 = (const float*)d_in[7];
    const float* Wk1 = (const float*)d_in[8];
    const float* Wv1 = (const float*)d_in[9];
    const float* ae1 = (const float*)d_in[10];
    const float* emb = (const float*)d_in[11];
    const float* Wq2 = (const float*)d_in[12];
    const float* bq2 = (const float*)d_in[13];
    const float* Wk2 = (const float*)d_in[14];
    const float* Wv2 = (const float*)d_in[15];
    const float* ae2 = (const float*)d_in[16];
    const float* W_agg = (const float*)d_in[17];
    const float* b_agg = (const float*)d_in[18];
    const float* W_self = (const float*)d_in[19];
    const int* uid1 = (const int*)d_in[20];
    const int* vid1 = (const int*)d_in[21];
    const int* cnt1 = (const int*)d_in[22];
    const int* uid2 = (const int*)d_in[23];
    const int* vid2 = (const int*)d_in[24];
    float* out = (float*)d_out;

    // single memset: stats (2KB) + hist + scan ticket (adjacent)
    hipMemsetAsync(ws + OFF_STATS, 0, 2048 + (size_t)NPAD * 4 + 64, stream);

    // 1. prologue: BN stats + dst histogram + pack weights + emb->bf16
    ProArgs pa;
    pa.w[0] = Wq1; pa.w[1] = Wk1; pa.w[2] = Wv1; pa.w[3] = Wk2;
    pa.w[4] = W_self; pa.w[5] = Wq2; pa.w[6] = Wv2; pa.w[7] = W_agg;
    pa.ft_item = ft_item; pa.ft_user = ft_user; pa.emb = emb;
    pa.vid1 = vid1; pa.vid2 = vid2;
    prologue<<<PRO_STAT + PRO_HIST + PRO_PACK + PRO_EMB, 256, 0, stream>>>(pa, ws);

    // 2+3. fused chunk scans + top-scan (ticket) + BN finalize (block 98)
    scan_fused<<<99, 1024, 0, stream>>>(bng_i, bnb_i, bng_u, bnb_u, ae1, ae2, ws);

    // 4+5. all 7 node-transform GEMMs + co-scheduled edge scatter (tail)
    TArgs ti, tu;
    ti.x = ft_item; ti.bias0 = bq1; ti.N = N_ITEM; ti.scaleOff = 0; ti.nmat = 5;
    ti.wtIdx[0] = 0; ti.wtIdx[1] = 1; ti.wtIdx[2] = 2; ti.wtIdx[3] = 3; ti.wtIdx[4] = 4;
    unsigned short* QC = (unsigned short*)(ws + OFF_QC);
    unsigned short* VC = (unsigned short*)(ws + OFF_VC);
    ti.out[0] = QC;
    ti.out[1] = (unsigned short*)(ws + OFF_K1);
    ti.out[2] = VC;
    ti.out[3] = (unsigned short*)(ws + OFF_K2);
    ti.out[4] = (unsigned short*)(ws + OFF_SELF);
    tu.x = ft_user; tu.bias0 = bq2; tu.N = N_USER; tu.scaleOff = 256; tu.nmat = 2;
    tu.wtIdx[0] = 5; tu.wtIdx[1] = 6; tu.wtIdx[2] = 0; tu.wtIdx[3] = 0; tu.wtIdx[4] = 0;
    tu.out[0] = QC + (size_t)N_ITEM * 128;
    tu.out[1] = VC + (size_t)N_ITEM * 128;
    tu.out[2] = tu.out[3] = tu.out[4] = tu.out[0];
    ScArgs sa;
    sa.uid1 = uid1; sa.vid1 = vid1; sa.cnt1 = cnt1; sa.uid2 = uid2; sa.vid2 = vid2;
    transform<<<TB_I + TB_U + SC_B, 256, 0, stream>>>(ti, tu, sa, ws);

    // 6. fused edge softmax+aggregate (4 slots/wave, 16B loads)
    edge_agg<<<(N_ITEM + 3) / 4, 256, 0, stream>>>(ae1, ae2, ws);

    // 7. final GEMM + self + relu (direct stores, 128 rows/block)
    final_mfma<<<(N_ITEM + 127) / 128, 256, 0, stream>>>(b_agg, out, ws);
}